// Round 6
// baseline (579.018 us; speedup 1.0000x reference)
//
#include <hip/hip_runtime.h>
#include <hip/hip_bf16.h>

// ---------------------------------------------------------------------------
// TriangularSelfAttention fused kernel (round 6 = round 5 + macro fix).
// One block per batch (4096 blocks), 512 threads = 8 waves, LDS = 79.8 KB
// (2 blocks/CU). Qpk/Kpk/va reg arrays -> NAMED SCALARS via macro unrolling
// (guide rule #20: runtime-indexed arrays go to scratch; the 1.06 GB
// WRITE_SIZE of rounds 3-4 was exactly that spill traffic).
// Fix vs round 5: nested FOR12 needs a second macro name (preprocessor
// forbids recursive expansion of the same macro).
// ---------------------------------------------------------------------------

typedef __bf16 bf8 __attribute__((ext_vector_type(8)));
typedef float f32x4 __attribute__((ext_vector_type(4)));
typedef unsigned int u32x4 __attribute__((ext_vector_type(4)));
typedef unsigned int u32x2 __attribute__((ext_vector_type(2)));

#define LDS_BYTES 79808
#define OFF_XT 0
#define OFF_O  27360
#define OFF_VT 54720
#define XS 72     // XT row stride (elements)
#define OS 72     // O  row stride
#define VS 196    // VT row stride

__device__ __forceinline__ unsigned short f2b(float f) {
  return __builtin_bit_cast(unsigned short, __float2bfloat16(f));
}
__device__ __forceinline__ float b2f(unsigned short u) {
  unsigned int x = (unsigned int)u << 16;
  return __builtin_bit_cast(float, x);
}
__device__ __forceinline__ unsigned int pk(float lo, float hi) {
  return (unsigned int)f2b(lo) | ((unsigned int)f2b(hi) << 16);
}
__device__ __forceinline__ bf8 ldsb8(const unsigned short* p) {
  u32x4 u = *(const u32x4*)p;
  return __builtin_bit_cast(bf8, u);
}
__device__ __forceinline__ bf8 as_bf8(u32x4 u) { return __builtin_bit_cast(bf8, u); }
__device__ __forceinline__ f32x4 mfma16(bf8 a, bf8 b, f32x4 c) {
  return __builtin_amdgcn_mfma_f32_16x16x32_bf16(a, b, c, 0, 0, 0);
}
__device__ __forceinline__ bf8 load_w8(const float* p) {   // 8 consecutive f32 -> bf8
  float4 a = ((const float4*)p)[0];
  float4 b = ((const float4*)p)[1];
  u32x4 u = { pk(a.x, a.y), pk(a.z, a.w), pk(b.x, b.y), pk(b.z, b.w) };
  return __builtin_bit_cast(bf8, u);
}
// triangular row index: i s.t. base(i) <= s < base(i+1), base(i)=i*(39-i)/2
__device__ __forceinline__ int tri_row(int s) {
  int i = (int)floorf((39.0f - sqrtf(1521.0f - 8.0f * (float)s)) * 0.5f);
  if (s < i * (39 - i) / 2) --i;
  else if (s >= (i + 1) * (38 - i) / 2) ++i;
  return i;
}

#define FOR12(M)  M(0) M(1) M(2) M(3) M(4) M(5) M(6) M(7) M(8) M(9) M(10) M(11)
#define FOR12B(M) M(0) M(1) M(2) M(3) M(4) M(5) M(6) M(7) M(8) M(9) M(10) M(11)

__global__ void __launch_bounds__(512)
__attribute__((amdgpu_waves_per_eu(4, 4)))
tri_attn_kernel(const float* __restrict__ x, const float* __restrict__ pos,
                const float* __restrict__ w_in, const float* __restrict__ b_in,
                const float* __restrict__ w_out, const float* __restrict__ b_out,
                const float* __restrict__ ln_g, const float* __restrict__ ln_b,
                float* __restrict__ out)
{
  extern __shared__ char lds[];
  unsigned short* XT = (unsigned short*)(lds + OFF_XT);   // [190][72] x+pos; later Z
  unsigned short* OB = (unsigned short*)(lds + OFF_O);    // [190][72] attention out
  unsigned short* VT = (unsigned short*)(lds + OFF_VT);   // [64][196] V transposed

  const int tid  = threadIdx.x;
  const int lane = tid & 63;
  const int wv   = tid >> 6;      // wave = head
  const int q15  = lane & 15;
  const int g    = lane >> 4;
  const int b    = blockIdx.x;
  // (1/sqrt(8)) * log2(e): softmax via exp2, normalization cancels the base swap
  const float qscale = 0.5100694858979282f;

  // ---------------- P0: gather x + pos_emb -> XT (bf16) ----------------
  const float* xb = x + (size_t)b * (361 * 64);
  for (int idx = tid; idx < 3040; idx += 512) {            // 190 rows * 16 float4
    int s = idx >> 4, c = idx & 15;
    int i = tri_row(s);
    int j = i + s - i * (39 - i) / 2;
    float4 v = ((const float4*)(xb + (i * 19 + j) * 64))[c];
    float4 p = ((const float4*)(pos + s * 64))[c];
    u32x2 wd = { pk(v.x + p.x, v.y + p.y), pk(v.z + p.z, v.w + p.w) };
    *(u32x2*)(XT + s * XS + c * 4) = wd;
  }
  if (tid < 64) *(unsigned int*)(VT + tid * VS + 190) = 0u;  // zero VT keys 190,191
  __syncthreads();

  // ---------------- P1: projections ----------------
  const int t   = wv >> 1;       // head-pair row-tile (dims 16t..16t+15)
  const int hh  = wv & 1;        // which half of the pair is my head
  const int nt  = wv & 3;        // V/out-proj n-tile
  const int mtb = wv >> 2;       // V/out-proj m-tile base (0 or 1)
  const bool keep = ((g >> 1) == hh);

  // named per-tile fragments (rule #20: no runtime-indexed arrays)
  #define DECL_QKV(I) unsigned int q##I##a, q##I##b, k##I##a, k##I##b, v##I##x, v##I##y;
  FOR12(DECL_QKV)

  // Q^T = W_q . X^T  (C: col=query, row=q-dim). Kept in registers (packed bf16).
  {
    bf8 wq0 = load_w8(w_in + (t * 16 + q15) * 64 + g * 8);
    bf8 wq1 = load_w8(w_in + (t * 16 + q15) * 64 + 32 + g * 8);
    float bq0 = b_in[t * 16 + g * 4 + 0], bq1 = b_in[t * 16 + g * 4 + 1];
    float bq2 = b_in[t * 16 + g * 4 + 2], bq3 = b_in[t * 16 + g * 4 + 3];
    #define QPROJ(I) { \
      f32x4 acc = {0.f, 0.f, 0.f, 0.f}; \
      acc = mfma16(wq0, ldsb8(XT + ((I) * 16 + q15) * XS + g * 8), acc); \
      acc = mfma16(wq1, ldsb8(XT + ((I) * 16 + q15) * XS + 32 + g * 8), acc); \
      float v0 = keep ? (acc[0] + bq0) * qscale : 0.f; \
      float v1 = keep ? (acc[1] + bq1) * qscale : 0.f; \
      float v2 = keep ? (acc[2] + bq2) * qscale : 0.f; \
      float v3 = keep ? (acc[3] + bq3) * qscale : 0.f; \
      q##I##a = pk(v0, v1); q##I##b = pk(v2, v3); }
    FOR12(QPROJ)
  }

  // K^T = W_k . X^T  (C: col=key, row=k-dim). Kept in registers.
  {
    bf8 wk0 = load_w8(w_in + (64 + t * 16 + q15) * 64 + g * 8);
    bf8 wk1 = load_w8(w_in + (64 + t * 16 + q15) * 64 + 32 + g * 8);
    float bk0 = b_in[64 + t * 16 + g * 4 + 0], bk1 = b_in[64 + t * 16 + g * 4 + 1];
    float bk2 = b_in[64 + t * 16 + g * 4 + 2], bk3 = b_in[64 + t * 16 + g * 4 + 3];
    #define KPROJ(I) { \
      f32x4 acc = {0.f, 0.f, 0.f, 0.f}; \
      acc = mfma16(wk0, ldsb8(XT + ((I) * 16 + q15) * XS + g * 8), acc); \
      acc = mfma16(wk1, ldsb8(XT + ((I) * 16 + q15) * XS + 32 + g * 8), acc); \
      k##I##a = pk(acc[0] + bk0, acc[1] + bk1); \
      k##I##b = pk(acc[2] + bk2, acc[3] + bk3); }
    FOR12(KPROJ)
  }

  // V = X . W_v^T (normal orientation; C: col=v-dim, row=key) -> VT[dim][key]
  {
    bf8 wv0 = load_w8(w_in + (128 + nt * 16 + q15) * 64 + g * 8);
    bf8 wv1 = load_w8(w_in + (128 + nt * 16 + q15) * 64 + 32 + g * 8);
    float bv = b_in[128 + nt * 16 + q15];
    #pragma unroll
    for (int m6 = 0; m6 < 6; ++m6) {
      int mt = mtb + 2 * m6;
      f32x4 acc = {bv, bv, bv, bv};
      acc = mfma16(ldsb8(XT + (mt * 16 + q15) * XS + g * 8), wv0, acc);
      acc = mfma16(ldsb8(XT + (mt * 16 + q15) * XS + 32 + g * 8), wv1, acc);
      unsigned int w0 = pk(acc[0], acc[1]), w1 = pk(acc[2], acc[3]);
      unsigned short* dst = VT + (nt * 16 + q15) * VS + mt * 16 + g * 4;
      if (mt == 11 && g == 3) {            // keys 188,189 only (190,191 stay 0)
        *(unsigned int*)dst = w0;
      } else {
        u32x2 wd = {w0, w1};
        *(u32x2*)dst = wd;
      }
    }
  }
  __syncthreads();

  // ---------------- P2: attention (all in registers, O -> LDS) ----------------
  const int h = wv;
  const bool mk3 = (g == 3);
  #define VLOAD(I) { \
    u32x2 t_ = *(const u32x2*)(VT + (h * 8 + (q15 & 7)) * VS + (I) * 16 + g * 4); \
    v##I##x = t_.x; v##I##y = t_.y; }
  FOR12(VLOAD)

  #define ATT_K(KT) { \
    u32x4 ka = {k##KT##a, k##KT##b, 0u, 0u}; \
    f32x4 sc = mfma16(as_bf8(ka), qb8, f32x4{0.f, 0.f, 0.f, 0.f}); \
    float p0 = __builtin_amdgcn_exp2f(sc[0]); \
    float p1 = __builtin_amdgcn_exp2f(sc[1]); \
    float p2 = __builtin_amdgcn_exp2f(sc[2]); \
    float p3 = __builtin_amdgcn_exp2f(sc[3]); \
    if ((KT) == 11) { p2 = mk3 ? 0.f : p2; p3 = mk3 ? 0.f : p3; } \
    S += (p0 + p1) + (p2 + p3); \
    u32x4 pb = {pk(p0, p1), pk(p2, p3), 0u, 0u}; \
    u32x4 aa = {v##KT##x, v##KT##y, 0u, 0u}; \
    o = mfma16(as_bf8(aa), as_bf8(pb), o); }

  #define ATT_MC(MC) { \
    u32x4 qb = {q##MC##a, q##MC##b, 0u, 0u}; \
    bf8 qb8 = as_bf8(qb); \
    f32x4 o = {0.f, 0.f, 0.f, 0.f}; \
    float S = 0.f; \
    FOR12B(ATT_K) \
    S += __shfl_xor(S, 16); \
    S += __shfl_xor(S, 32); \
    float inv = __builtin_amdgcn_rcpf(S); \
    int qa = (MC) * 16 + q15; \
    if (g < 2 && qa < 190) { \
      u32x2 wd = { pk(o[0] * inv, o[1] * inv), pk(o[2] * inv, o[3] * inv) }; \
      *(u32x2*)(OB + qa * OS + h * 8 + g * 4) = wd; } }

  FOR12(ATT_MC)
  __syncthreads();

  // ---------------- P3: out-proj + residual (Z in-place into XT) ----------------
  {
    bf8 wo0 = load_w8(w_out + (nt * 16 + q15) * 64 + g * 8);
    bf8 wo1 = load_w8(w_out + (nt * 16 + q15) * 64 + 32 + g * 8);
    float bo = b_out[nt * 16 + q15];
    #pragma unroll
    for (int m6 = 0; m6 < 6; ++m6) {
      int mt = mtb + 2 * m6;
      f32x4 acc = {bo, bo, bo, bo};
      acc = mfma16(ldsb8(OB + (mt * 16 + q15) * OS + g * 8), wo0, acc);
      acc = mfma16(ldsb8(OB + (mt * 16 + q15) * OS + 32 + g * 8), wo1, acc);
      #pragma unroll
      for (int r = 0; r < 4; ++r) {
        int row = mt * 16 + g * 4 + r;
        if (row < 190) {
          int col = nt * 16 + q15;
          float z = acc[r] + b2f(XT[row * XS + col]);
          XT[row * XS + col] = f2b(z);
        }
      }
    }
  }
  __syncthreads();

  // ---------------- P4: LayerNorm + symmetric scatter ----------------
  float gg = ln_g[lane];
  float bb = ln_b[lane];
  float* outb = out + (size_t)b * (361 * 64);
  for (int s = wv; s < 190; s += 8) {
    float zv = b2f(XT[s * XS + lane]);
    float sum = zv;
    #pragma unroll
    for (int m = 1; m < 64; m <<= 1) sum += __shfl_xor(sum, m);
    float mu = sum * 0.015625f;
    float dv = zv - mu;
    float s2 = dv * dv;
    #pragma unroll
    for (int m = 1; m < 64; m <<= 1) s2 += __shfl_xor(s2, m);
    float y = dv * rsqrtf(s2 * 0.015625f + 1e-5f) * gg + bb;
    int i = tri_row(s);
    int j = i + s - i * (39 - i) / 2;
    outb[(i * 19 + j) * 64 + lane] = y;
    outb[(j * 19 + i) * 64 + lane] = y;     // mirror (diagonal rewritten, same value)
  }
}

extern "C" void kernel_launch(void* const* d_in, const int* in_sizes, int n_in,
                              void* d_out, int out_size, void* d_ws, size_t ws_size,
                              hipStream_t stream) {
  const float* x     = (const float*)d_in[0];
  const float* pos   = (const float*)d_in[1];
  const float* w_in  = (const float*)d_in[2];
  const float* b_in  = (const float*)d_in[3];
  const float* w_out = (const float*)d_in[4];
  const float* b_out = (const float*)d_in[5];
  const float* ln_g  = (const float*)d_in[6];
  const float* ln_b  = (const float*)d_in[7];
  float* out = (float*)d_out;
  (void)in_sizes; (void)n_in; (void)out_size; (void)d_ws; (void)ws_size;
  hipFuncSetAttribute((const void*)tri_attn_kernel,
                      hipFuncAttributeMaxDynamicSharedMemorySize, LDS_BYTES);
  tri_attn_kernel<<<4096, 512, LDS_BYTES, stream>>>(x, pos, w_in, b_in, w_out,
                                                    b_out, ln_g, ln_b, out);
}

// Round 7
// 469.620 us; speedup vs baseline: 1.2329x; 1.2329x over previous
//
#include <hip/hip_runtime.h>
#include <hip/hip_bf16.h>

// ---------------------------------------------------------------------------
// TriangularSelfAttention fused kernel (round 7).
// One block per batch (4096 blocks), 512 threads = 8 waves, LDS = 79.8 KB
// (2 blocks/CU). Round-7 change: Q moves from registers to LDS (OB region,
// in-place Q->O swap per wave). Cuts peak VGPR pressure ~120 -> ~85, which
// should eliminate the allocator-spill traffic (rounds 3-6: +700 MB WRITE).
// Bonus: Q computed once (normal orientation) instead of twice (transposed
// per wave-pair) -> 20% less P1 MFMA work.
// ---------------------------------------------------------------------------

typedef __bf16 bf8 __attribute__((ext_vector_type(8)));
typedef float f32x4 __attribute__((ext_vector_type(4)));
typedef unsigned int u32x4 __attribute__((ext_vector_type(4)));
typedef unsigned int u32x2 __attribute__((ext_vector_type(2)));

#define LDS_BYTES 79808
#define OFF_XT 0
#define OFF_O  27360
#define OFF_VT 54720
#define XS 72     // XT row stride (elements)
#define OS 72     // O/Q row stride
#define VS 196    // VT row stride

__device__ __forceinline__ unsigned short f2b(float f) {
  return __builtin_bit_cast(unsigned short, __float2bfloat16(f));
}
__device__ __forceinline__ float b2f(unsigned short u) {
  unsigned int x = (unsigned int)u << 16;
  return __builtin_bit_cast(float, x);
}
__device__ __forceinline__ unsigned int pk(float lo, float hi) {
  return (unsigned int)f2b(lo) | ((unsigned int)f2b(hi) << 16);
}
__device__ __forceinline__ bf8 ldsb8(const unsigned short* p) {
  u32x4 u = *(const u32x4*)p;
  return __builtin_bit_cast(bf8, u);
}
__device__ __forceinline__ bf8 as_bf8(u32x4 u) { return __builtin_bit_cast(bf8, u); }
__device__ __forceinline__ f32x4 mfma16(bf8 a, bf8 b, f32x4 c) {
  return __builtin_amdgcn_mfma_f32_16x16x32_bf16(a, b, c, 0, 0, 0);
}
__device__ __forceinline__ bf8 load_w8(const float* p) {   // 8 consecutive f32 -> bf8
  float4 a = ((const float4*)p)[0];
  float4 b = ((const float4*)p)[1];
  u32x4 u = { pk(a.x, a.y), pk(a.z, a.w), pk(b.x, b.y), pk(b.z, b.w) };
  return __builtin_bit_cast(bf8, u);
}
// triangular row index: i s.t. base(i) <= s < base(i+1), base(i)=i*(39-i)/2
__device__ __forceinline__ int tri_row(int s) {
  int i = (int)floorf((39.0f - sqrtf(1521.0f - 8.0f * (float)s)) * 0.5f);
  if (s < i * (39 - i) / 2) --i;
  else if (s >= (i + 1) * (38 - i) / 2) ++i;
  return i;
}

#define FOR12(M)  M(0) M(1) M(2) M(3) M(4) M(5) M(6) M(7) M(8) M(9) M(10) M(11)
#define FOR12B(M) M(0) M(1) M(2) M(3) M(4) M(5) M(6) M(7) M(8) M(9) M(10) M(11)

__global__ void __launch_bounds__(512)
__attribute__((amdgpu_waves_per_eu(4, 4)))
tri_attn_kernel(const float* __restrict__ x, const float* __restrict__ pos,
                const float* __restrict__ w_in, const float* __restrict__ b_in,
                const float* __restrict__ w_out, const float* __restrict__ b_out,
                const float* __restrict__ ln_g, const float* __restrict__ ln_b,
                float* __restrict__ out)
{
  extern __shared__ char lds[];
  unsigned short* XT = (unsigned short*)(lds + OFF_XT);   // [190][72] x+pos; later Z
  unsigned short* OB = (unsigned short*)(lds + OFF_O);    // [190][72] Q, then O in-place
  unsigned short* VT = (unsigned short*)(lds + OFF_VT);   // [64][196] V transposed

  const int tid  = threadIdx.x;
  const int lane = tid & 63;
  const int wv   = tid >> 6;      // wave = head
  const int q15  = lane & 15;
  const int g    = lane >> 4;
  const int b    = blockIdx.x;
  // (1/sqrt(8)) * log2(e): softmax via exp2, normalization cancels the base swap
  const float qscale = 0.5100694858979282f;

  // ---------------- P0: gather x + pos_emb -> XT (bf16) ----------------
  const float* xb = x + (size_t)b * (361 * 64);
  for (int idx = tid; idx < 3040; idx += 512) {            // 190 rows * 16 float4
    int s = idx >> 4, c = idx & 15;
    int i = tri_row(s);
    int j = i + s - i * (39 - i) / 2;
    float4 v = ((const float4*)(xb + (i * 19 + j) * 64))[c];
    float4 p = ((const float4*)(pos + s * 64))[c];
    u32x2 wd = { pk(v.x + p.x, v.y + p.y), pk(v.z + p.z, v.w + p.w) };
    *(u32x2*)(XT + s * XS + c * 4) = wd;
  }
  if (tid < 64) *(unsigned int*)(VT + tid * VS + 190) = 0u;  // zero VT keys 190,191
  __syncthreads();

  // ---------------- P1: projections ----------------
  const int t   = wv >> 1;       // head-pair row-tile (kdims 16t..16t+15)
  const int hh  = wv & 1;        // which half of the pair is my head
  const int nt  = wv & 3;        // Q/V/out-proj n-tile
  const int mtb = wv >> 2;       // Q/V/out-proj m-tile base (0 or 1)
  const bool keep = ((g >> 1) == hh);

  // named per-tile fragments for K and V (allocator-friendly, all static)
  #define DECL_KV(I) unsigned int k##I##a, k##I##b, v##I##x, v##I##y;
  FOR12(DECL_KV)

  // Q = X . W_q^T (normal orientation; C: col=qdim, row=query) -> OB[query][qdim]
  {
    bf8 wq0 = load_w8(w_in + (nt * 16 + q15) * 64 + g * 8);
    bf8 wq1 = load_w8(w_in + (nt * 16 + q15) * 64 + 32 + g * 8);
    float bq = b_in[nt * 16 + q15];
    #pragma unroll
    for (int m6 = 0; m6 < 6; ++m6) {
      int mt = mtb + 2 * m6;
      f32x4 acc = {bq, bq, bq, bq};
      acc = mfma16(ldsb8(XT + (mt * 16 + q15) * XS + g * 8), wq0, acc);
      acc = mfma16(ldsb8(XT + (mt * 16 + q15) * XS + 32 + g * 8), wq1, acc);
      #pragma unroll
      for (int r = 0; r < 4; ++r) {
        int row = mt * 16 + g * 4 + r;
        if (row < 190) OB[row * OS + nt * 16 + q15] = f2b(acc[r] * qscale);
      }
    }
  }

  // K^T = W_k . X^T (C: col=key, row=kdim of the head PAIR). Kept in registers.
  {
    bf8 wk0 = load_w8(w_in + (64 + t * 16 + q15) * 64 + g * 8);
    bf8 wk1 = load_w8(w_in + (64 + t * 16 + q15) * 64 + 32 + g * 8);
    float bk0 = b_in[64 + t * 16 + g * 4 + 0], bk1 = b_in[64 + t * 16 + g * 4 + 1];
    float bk2 = b_in[64 + t * 16 + g * 4 + 2], bk3 = b_in[64 + t * 16 + g * 4 + 3];
    #define KPROJ(I) { \
      f32x4 acc = {0.f, 0.f, 0.f, 0.f}; \
      acc = mfma16(wk0, ldsb8(XT + ((I) * 16 + q15) * XS + g * 8), acc); \
      acc = mfma16(wk1, ldsb8(XT + ((I) * 16 + q15) * XS + 32 + g * 8), acc); \
      k##I##a = pk(acc[0] + bk0, acc[1] + bk1); \
      k##I##b = pk(acc[2] + bk2, acc[3] + bk3); }
    FOR12(KPROJ)
  }

  // V = X . W_v^T (C: col=vdim, row=key) -> VT[dim][key]
  {
    bf8 wv0 = load_w8(w_in + (128 + nt * 16 + q15) * 64 + g * 8);
    bf8 wv1 = load_w8(w_in + (128 + nt * 16 + q15) * 64 + 32 + g * 8);
    float bv = b_in[128 + nt * 16 + q15];
    #pragma unroll
    for (int m6 = 0; m6 < 6; ++m6) {
      int mt = mtb + 2 * m6;
      f32x4 acc = {bv, bv, bv, bv};
      acc = mfma16(ldsb8(XT + (mt * 16 + q15) * XS + g * 8), wv0, acc);
      acc = mfma16(ldsb8(XT + (mt * 16 + q15) * XS + 32 + g * 8), wv1, acc);
      unsigned int w0 = pk(acc[0], acc[1]), w1 = pk(acc[2], acc[3]);
      unsigned short* dst = VT + (nt * 16 + q15) * VS + mt * 16 + g * 4;
      if (mt == 11 && g == 3) {            // keys 188,189 only (190,191 stay 0)
        *(unsigned int*)dst = w0;
      } else {
        u32x2 wd = {w0, w1};
        *(u32x2*)dst = wd;
      }
    }
  }
  __syncthreads();

  // ---------------- P2: attention (K,V in regs; Q from LDS; O in-place) -------
  // Race-free in-place Q->O: wave h writes O only to cols h*8..h*8+7; the only
  // other wave reading those cols (its pair partner) masks them to zero (keep).
  const int h = wv;
  const bool mk3 = (g == 3);
  #define VLOAD(I) { \
    u32x2 t_ = *(const u32x2*)(VT + (h * 8 + (q15 & 7)) * VS + (I) * 16 + g * 4); \
    v##I##x = t_.x; v##I##y = t_.y; }
  FOR12(VLOAD)

  #define ATT_K(KT) { \
    u32x4 ka = {k##KT##a, k##KT##b, 0u, 0u}; \
    f32x4 sc = mfma16(as_bf8(ka), qb8, f32x4{0.f, 0.f, 0.f, 0.f}); \
    float p0 = __builtin_amdgcn_exp2f(sc[0]); \
    float p1 = __builtin_amdgcn_exp2f(sc[1]); \
    float p2 = __builtin_amdgcn_exp2f(sc[2]); \
    float p3 = __builtin_amdgcn_exp2f(sc[3]); \
    if ((KT) == 11) { p2 = mk3 ? 0.f : p2; p3 = mk3 ? 0.f : p3; } \
    S += (p0 + p1) + (p2 + p3); \
    u32x4 pb = {pk(p0, p1), pk(p2, p3), 0u, 0u}; \
    u32x4 aa = {v##KT##x, v##KT##y, 0u, 0u}; \
    o = mfma16(as_bf8(aa), as_bf8(pb), o); }

  #define ATT_MC(MC) { \
    u32x2 uq = *(const u32x2*)(OB + ((MC) * 16 + q15) * OS + t * 16 + g * 4); \
    u32x4 qb = {keep ? uq.x : 0u, keep ? uq.y : 0u, 0u, 0u}; \
    bf8 qb8 = as_bf8(qb); \
    f32x4 o = {0.f, 0.f, 0.f, 0.f}; \
    float S = 0.f; \
    FOR12B(ATT_K) \
    S += __shfl_xor(S, 16); \
    S += __shfl_xor(S, 32); \
    float inv = __builtin_amdgcn_rcpf(S); \
    int qa = (MC) * 16 + q15; \
    if (g < 2 && qa < 190) { \
      u32x2 wd = { pk(o[0] * inv, o[1] * inv), pk(o[2] * inv, o[3] * inv) }; \
      *(u32x2*)(OB + qa * OS + h * 8 + g * 4) = wd; } }

  FOR12(ATT_MC)
  __syncthreads();

  // ---------------- P3: out-proj + residual (Z in-place into XT) ----------------
  {
    bf8 wo0 = load_w8(w_out + (nt * 16 + q15) * 64 + g * 8);
    bf8 wo1 = load_w8(w_out + (nt * 16 + q15) * 64 + 32 + g * 8);
    float bo = b_out[nt * 16 + q15];
    #pragma unroll
    for (int m6 = 0; m6 < 6; ++m6) {
      int mt = mtb + 2 * m6;
      f32x4 acc = {bo, bo, bo, bo};
      acc = mfma16(ldsb8(OB + (mt * 16 + q15) * OS + g * 8), wo0, acc);
      acc = mfma16(ldsb8(OB + (mt * 16 + q15) * OS + 32 + g * 8), wo1, acc);
      #pragma unroll
      for (int r = 0; r < 4; ++r) {
        int row = mt * 16 + g * 4 + r;
        if (row < 190) {
          int col = nt * 16 + q15;
          float z = acc[r] + b2f(XT[row * XS + col]);
          XT[row * XS + col] = f2b(z);
        }
      }
    }
  }
  __syncthreads();

  // ---------------- P4: LayerNorm + symmetric scatter ----------------
  float gg = ln_g[lane];
  float bb = ln_b[lane];
  float* outb = out + (size_t)b * (361 * 64);
  for (int s = wv; s < 190; s += 8) {
    float zv = b2f(XT[s * XS + lane]);
    float sum = zv;
    #pragma unroll
    for (int m = 1; m < 64; m <<= 1) sum += __shfl_xor(sum, m);
    float mu = sum * 0.015625f;
    float dv = zv - mu;
    float s2 = dv * dv;
    #pragma unroll
    for (int m = 1; m < 64; m <<= 1) s2 += __shfl_xor(s2, m);
    float y = dv * rsqrtf(s2 * 0.015625f + 1e-5f) * gg + bb;
    int i = tri_row(s);
    int j = i + s - i * (39 - i) / 2;
    outb[(i * 19 + j) * 64 + lane] = y;
    outb[(j * 19 + i) * 64 + lane] = y;     // mirror (diagonal rewritten, same value)
  }
}

extern "C" void kernel_launch(void* const* d_in, const int* in_sizes, int n_in,
                              void* d_out, int out_size, void* d_ws, size_t ws_size,
                              hipStream_t stream) {
  const float* x     = (const float*)d_in[0];
  const float* pos   = (const float*)d_in[1];
  const float* w_in  = (const float*)d_in[2];
  const float* b_in  = (const float*)d_in[3];
  const float* w_out = (const float*)d_in[4];
  const float* b_out = (const float*)d_in[5];
  const float* ln_g  = (const float*)d_in[6];
  const float* ln_b  = (const float*)d_in[7];
  float* out = (float*)d_out;
  (void)in_sizes; (void)n_in; (void)out_size; (void)d_ws; (void)ws_size;
  hipFuncSetAttribute((const void*)tri_attn_kernel,
                      hipFuncAttributeMaxDynamicSharedMemorySize, LDS_BYTES);
  tri_attn_kernel<<<4096, 512, LDS_BYTES, stream>>>(x, pos, w_in, b_in, w_out,
                                                    b_out, ln_g, ln_b, out);
}

// Round 8
// 462.261 us; speedup vs baseline: 1.2526x; 1.0159x over previous
//
#include <hip/hip_runtime.h>
#include <hip/hip_bf16.h>

// ---------------------------------------------------------------------------
// TriangularSelfAttention fused kernel (round 8).
// One block per batch (4096 blocks), 512 threads = 8 waves, LDS = 79.8 KB
// (2 blocks/CU). Round-8 changes vs round 7:
//  (1) V no longer cached in persistent registers -> read from VT inside the
//      inner loop (persistent set K=24 + temps ~45 < 64-reg budget -> the
//      residual ~98 MB spill WRITE traffic should vanish).
//  (2) P2 critical path halved: o and S split into even/odd independent
//      accumulator chains (12 dependent MFMAs -> 2x6; 48-add chain -> 2x24).
// ---------------------------------------------------------------------------

typedef __bf16 bf8 __attribute__((ext_vector_type(8)));
typedef float f32x4 __attribute__((ext_vector_type(4)));
typedef unsigned int u32x4 __attribute__((ext_vector_type(4)));
typedef unsigned int u32x2 __attribute__((ext_vector_type(2)));

#define LDS_BYTES 79808
#define OFF_XT 0
#define OFF_O  27360
#define OFF_VT 54720
#define XS 72     // XT row stride (elements)
#define OS 72     // O/Q row stride
#define VS 196    // VT row stride

__device__ __forceinline__ unsigned short f2b(float f) {
  return __builtin_bit_cast(unsigned short, __float2bfloat16(f));
}
__device__ __forceinline__ float b2f(unsigned short u) {
  unsigned int x = (unsigned int)u << 16;
  return __builtin_bit_cast(float, x);
}
__device__ __forceinline__ unsigned int pk(float lo, float hi) {
  return (unsigned int)f2b(lo) | ((unsigned int)f2b(hi) << 16);
}
__device__ __forceinline__ bf8 ldsb8(const unsigned short* p) {
  u32x4 u = *(const u32x4*)p;
  return __builtin_bit_cast(bf8, u);
}
__device__ __forceinline__ bf8 as_bf8(u32x4 u) { return __builtin_bit_cast(bf8, u); }
__device__ __forceinline__ f32x4 mfma16(bf8 a, bf8 b, f32x4 c) {
  return __builtin_amdgcn_mfma_f32_16x16x32_bf16(a, b, c, 0, 0, 0);
}
__device__ __forceinline__ bf8 load_w8(const float* p) {   // 8 consecutive f32 -> bf8
  float4 a = ((const float4*)p)[0];
  float4 b = ((const float4*)p)[1];
  u32x4 u = { pk(a.x, a.y), pk(a.z, a.w), pk(b.x, b.y), pk(b.z, b.w) };
  return __builtin_bit_cast(bf8, u);
}
// triangular row index: i s.t. base(i) <= s < base(i+1), base(i)=i*(39-i)/2
__device__ __forceinline__ int tri_row(int s) {
  int i = (int)floorf((39.0f - sqrtf(1521.0f - 8.0f * (float)s)) * 0.5f);
  if (s < i * (39 - i) / 2) --i;
  else if (s >= (i + 1) * (38 - i) / 2) ++i;
  return i;
}

#define FOR12(M)  M(0) M(1) M(2) M(3) M(4) M(5) M(6) M(7) M(8) M(9) M(10) M(11)

__global__ void __launch_bounds__(512)
__attribute__((amdgpu_waves_per_eu(4, 4)))
tri_attn_kernel(const float* __restrict__ x, const float* __restrict__ pos,
                const float* __restrict__ w_in, const float* __restrict__ b_in,
                const float* __restrict__ w_out, const float* __restrict__ b_out,
                const float* __restrict__ ln_g, const float* __restrict__ ln_b,
                float* __restrict__ out)
{
  extern __shared__ char lds[];
  unsigned short* XT = (unsigned short*)(lds + OFF_XT);   // [190][72] x+pos; later Z
  unsigned short* OB = (unsigned short*)(lds + OFF_O);    // [190][72] Q, then O in-place
  unsigned short* VT = (unsigned short*)(lds + OFF_VT);   // [64][196] V transposed

  const int tid  = threadIdx.x;
  const int lane = tid & 63;
  const int wv   = tid >> 6;      // wave = head
  const int q15  = lane & 15;
  const int g    = lane >> 4;
  const int b    = blockIdx.x;
  // (1/sqrt(8)) * log2(e): softmax via exp2, normalization cancels the base swap
  const float qscale = 0.5100694858979282f;

  // ---------------- P0: gather x + pos_emb -> XT (bf16) ----------------
  const float* xb = x + (size_t)b * (361 * 64);
  for (int idx = tid; idx < 3040; idx += 512) {            // 190 rows * 16 float4
    int s = idx >> 4, c = idx & 15;
    int i = tri_row(s);
    int j = i + s - i * (39 - i) / 2;
    float4 v = ((const float4*)(xb + (i * 19 + j) * 64))[c];
    float4 p = ((const float4*)(pos + s * 64))[c];
    u32x2 wd = { pk(v.x + p.x, v.y + p.y), pk(v.z + p.z, v.w + p.w) };
    *(u32x2*)(XT + s * XS + c * 4) = wd;
  }
  if (tid < 64) *(unsigned int*)(VT + tid * VS + 190) = 0u;  // zero VT keys 190,191
  __syncthreads();

  // ---------------- P1: projections ----------------
  const int t   = wv >> 1;       // head-pair row-tile (kdims 16t..16t+15)
  const int hh  = wv & 1;        // which half of the pair is my head
  const int nt  = wv & 3;        // Q/V/out-proj n-tile
  const int mtb = wv >> 2;       // Q/V/out-proj m-tile base (0 or 1)
  const bool keep = ((g >> 1) == hh);

  // named K fragments (persistent through P2; V is re-read from LDS)
  #define DECL_K(I) unsigned int k##I##a, k##I##b;
  FOR12(DECL_K)

  // Q = X . W_q^T (normal orientation; C: col=qdim, row=query) -> OB[query][qdim]
  {
    bf8 wq0 = load_w8(w_in + (nt * 16 + q15) * 64 + g * 8);
    bf8 wq1 = load_w8(w_in + (nt * 16 + q15) * 64 + 32 + g * 8);
    float bq = b_in[nt * 16 + q15];
    #pragma unroll
    for (int m6 = 0; m6 < 6; ++m6) {
      int mt = mtb + 2 * m6;
      f32x4 acc = {bq, bq, bq, bq};
      acc = mfma16(ldsb8(XT + (mt * 16 + q15) * XS + g * 8), wq0, acc);
      acc = mfma16(ldsb8(XT + (mt * 16 + q15) * XS + 32 + g * 8), wq1, acc);
      #pragma unroll
      for (int r = 0; r < 4; ++r) {
        int row = mt * 16 + g * 4 + r;
        if (row < 190) OB[row * OS + nt * 16 + q15] = f2b(acc[r] * qscale);
      }
    }
  }

  // K^T = W_k . X^T (C: col=key, row=kdim of the head PAIR). Kept in registers.
  {
    bf8 wk0 = load_w8(w_in + (64 + t * 16 + q15) * 64 + g * 8);
    bf8 wk1 = load_w8(w_in + (64 + t * 16 + q15) * 64 + 32 + g * 8);
    float bk0 = b_in[64 + t * 16 + g * 4 + 0], bk1 = b_in[64 + t * 16 + g * 4 + 1];
    float bk2 = b_in[64 + t * 16 + g * 4 + 2], bk3 = b_in[64 + t * 16 + g * 4 + 3];
    #define KPROJ(I) { \
      f32x4 acc = {0.f, 0.f, 0.f, 0.f}; \
      acc = mfma16(wk0, ldsb8(XT + ((I) * 16 + q15) * XS + g * 8), acc); \
      acc = mfma16(wk1, ldsb8(XT + ((I) * 16 + q15) * XS + 32 + g * 8), acc); \
      k##I##a = pk(acc[0] + bk0, acc[1] + bk1); \
      k##I##b = pk(acc[2] + bk2, acc[3] + bk3); }
    FOR12(KPROJ)
  }

  // V = X . W_v^T (C: col=vdim, row=key) -> VT[dim][key]
  {
    bf8 wv0 = load_w8(w_in + (128 + nt * 16 + q15) * 64 + g * 8);
    bf8 wv1 = load_w8(w_in + (128 + nt * 16 + q15) * 64 + 32 + g * 8);
    float bv = b_in[128 + nt * 16 + q15];
    #pragma unroll
    for (int m6 = 0; m6 < 6; ++m6) {
      int mt = mtb + 2 * m6;
      f32x4 acc = {bv, bv, bv, bv};
      acc = mfma16(ldsb8(XT + (mt * 16 + q15) * XS + g * 8), wv0, acc);
      acc = mfma16(ldsb8(XT + (mt * 16 + q15) * XS + 32 + g * 8), wv1, acc);
      unsigned int w0 = pk(acc[0], acc[1]), w1 = pk(acc[2], acc[3]);
      unsigned short* dst = VT + (nt * 16 + q15) * VS + mt * 16 + g * 4;
      if (mt == 11 && g == 3) {            // keys 188,189 only (190,191 stay 0)
        *(unsigned int*)dst = w0;
      } else {
        u32x2 wd = {w0, w1};
        *(u32x2*)dst = wd;
      }
    }
  }
  __syncthreads();

  // ---------------- P2: attention (K in regs; Q,V from LDS; O in-place) -------
  // Race-free in-place Q->O: wave h writes O only to cols h*8..h*8+7; the only
  // other wave reading those cols (its pair partner) masks them to zero (keep).
  const int h = wv;
  const bool mk3 = (g == 3);
  const unsigned short* Vrow = VT + (h * 8 + (q15 & 7)) * VS;  // my V dim row

  #define ATT_K(KT, OA, SA) { \
    u32x4 ka = {k##KT##a, k##KT##b, 0u, 0u}; \
    f32x4 sc = mfma16(as_bf8(ka), qb8, f32x4{0.f, 0.f, 0.f, 0.f}); \
    u32x2 vt_ = *(const u32x2*)(Vrow + (KT) * 16 + g * 4); \
    float p0 = __builtin_amdgcn_exp2f(sc[0]); \
    float p1 = __builtin_amdgcn_exp2f(sc[1]); \
    float p2 = __builtin_amdgcn_exp2f(sc[2]); \
    float p3 = __builtin_amdgcn_exp2f(sc[3]); \
    if ((KT) == 11) { p2 = mk3 ? 0.f : p2; p3 = mk3 ? 0.f : p3; } \
    SA += (p0 + p1) + (p2 + p3); \
    u32x4 pb = {pk(p0, p1), pk(p2, p3), 0u, 0u}; \
    u32x4 aa = {vt_.x, vt_.y, 0u, 0u}; \
    OA = mfma16(as_bf8(aa), as_bf8(pb), OA); }

  #define ATT_MC(MC) { \
    u32x2 uq = *(const u32x2*)(OB + ((MC) * 16 + q15) * OS + t * 16 + g * 4); \
    u32x4 qb = {keep ? uq.x : 0u, keep ? uq.y : 0u, 0u, 0u}; \
    bf8 qb8 = as_bf8(qb); \
    f32x4 o0 = {0.f, 0.f, 0.f, 0.f}, o1 = {0.f, 0.f, 0.f, 0.f}; \
    float S0 = 0.f, S1 = 0.f; \
    ATT_K(0, o0, S0)  ATT_K(1, o1, S1)  ATT_K(2, o0, S0)  ATT_K(3, o1, S1) \
    ATT_K(4, o0, S0)  ATT_K(5, o1, S1)  ATT_K(6, o0, S0)  ATT_K(7, o1, S1) \
    ATT_K(8, o0, S0)  ATT_K(9, o1, S1)  ATT_K(10, o0, S0) ATT_K(11, o1, S1) \
    f32x4 o = o0 + o1; \
    float S = S0 + S1; \
    S += __shfl_xor(S, 16); \
    S += __shfl_xor(S, 32); \
    float inv = __builtin_amdgcn_rcpf(S); \
    int qa = (MC) * 16 + q15; \
    if (g < 2 && qa < 190) { \
      u32x2 wd = { pk(o[0] * inv, o[1] * inv), pk(o[2] * inv, o[3] * inv) }; \
      *(u32x2*)(OB + qa * OS + h * 8 + g * 4) = wd; } }

  FOR12(ATT_MC)
  __syncthreads();

  // ---------------- P3: out-proj + residual (Z in-place into XT) ----------------
  {
    bf8 wo0 = load_w8(w_out + (nt * 16 + q15) * 64 + g * 8);
    bf8 wo1 = load_w8(w_out + (nt * 16 + q15) * 64 + 32 + g * 8);
    float bo = b_out[nt * 16 + q15];
    #pragma unroll
    for (int m6 = 0; m6 < 6; ++m6) {
      int mt = mtb + 2 * m6;
      f32x4 acc = {bo, bo, bo, bo};
      acc = mfma16(ldsb8(OB + (mt * 16 + q15) * OS + g * 8), wo0, acc);
      acc = mfma16(ldsb8(OB + (mt * 16 + q15) * OS + 32 + g * 8), wo1, acc);
      #pragma unroll
      for (int r = 0; r < 4; ++r) {
        int row = mt * 16 + g * 4 + r;
        if (row < 190) {
          int col = nt * 16 + q15;
          float z = acc[r] + b2f(XT[row * XS + col]);
          XT[row * XS + col] = f2b(z);
        }
      }
    }
  }
  __syncthreads();

  // ---------------- P4: LayerNorm + symmetric scatter ----------------
  float gg = ln_g[lane];
  float bb = ln_b[lane];
  float* outb = out + (size_t)b * (361 * 64);
  for (int s = wv; s < 190; s += 8) {
    float zv = b2f(XT[s * XS + lane]);
    float sum = zv;
    #pragma unroll
    for (int m = 1; m < 64; m <<= 1) sum += __shfl_xor(sum, m);
    float mu = sum * 0.015625f;
    float dv = zv - mu;
    float s2 = dv * dv;
    #pragma unroll
    for (int m = 1; m < 64; m <<= 1) s2 += __shfl_xor(s2, m);
    float y = dv * rsqrtf(s2 * 0.015625f + 1e-5f) * gg + bb;
    int i = tri_row(s);
    int j = i + s - i * (39 - i) / 2;
    outb[(i * 19 + j) * 64 + lane] = y;
    outb[(j * 19 + i) * 64 + lane] = y;     // mirror (diagonal rewritten, same value)
  }
}

extern "C" void kernel_launch(void* const* d_in, const int* in_sizes, int n_in,
                              void* d_out, int out_size, void* d_ws, size_t ws_size,
                              hipStream_t stream) {
  const float* x     = (const float*)d_in[0];
  const float* pos   = (const float*)d_in[1];
  const float* w_in  = (const float*)d_in[2];
  const float* b_in  = (const float*)d_in[3];
  const float* w_out = (const float*)d_in[4];
  const float* b_out = (const float*)d_in[5];
  const float* ln_g  = (const float*)d_in[6];
  const float* ln_b  = (const float*)d_in[7];
  float* out = (float*)d_out;
  (void)in_sizes; (void)n_in; (void)out_size; (void)d_ws; (void)ws_size;
  hipFuncSetAttribute((const void*)tri_attn_kernel,
                      hipFuncAttributeMaxDynamicSharedMemorySize, LDS_BYTES);
  tri_attn_kernel<<<4096, 512, LDS_BYTES, stream>>>(x, pos, w_in, b_in, w_out,
                                                    b_out, ln_g, ln_b, out);
}

// Round 9
// 376.973 us; speedup vs baseline: 1.5360x; 1.2262x over previous
//
#include <hip/hip_runtime.h>
#include <hip/hip_bf16.h>

// ---------------------------------------------------------------------------
// TriangularSelfAttention fused kernel (round 9).
// One block per batch (4096 blocks), 512 threads = 8 waves, LDS = 80.2 KB
// (2 blocks/CU). Round-9 changes vs round 8:
//  (1) all f32->bf16 conversions use native __bf16 casts -> hardware
//      v_cvt_pk_bf16_f32 (the HIP __float2bfloat16 helper is a ~7-instr
//      software RNE sequence; ~450 calls/wave explained the 77% VALUBusy).
//  (2) softmax denominator computed by the PV MFMA via an all-ones V row
//      (VT row 64): C row 8 = sum_k P[k][q] = S. Kills the per-chunk
//      36-add + 2-shuffle S reduction; one __shfl(o[0], 32+q15) remains.
// ---------------------------------------------------------------------------

typedef __bf16 bf8 __attribute__((ext_vector_type(8)));
typedef __bf16 bf2 __attribute__((ext_vector_type(2)));
typedef float f32x4 __attribute__((ext_vector_type(4)));
typedef unsigned int u32x4 __attribute__((ext_vector_type(4)));
typedef unsigned int u32x2 __attribute__((ext_vector_type(2)));

#define LDS_BYTES 80200
#define OFF_XT 0
#define OFF_O  27360
#define OFF_VT 54720
#define XS 72     // XT row stride (elements)
#define OS 72     // O/Q row stride
#define VS 196    // VT row stride (rows 0..63 = v dims, row 64 = ones)

__device__ __forceinline__ unsigned short f2b(float f) {
  __bf16 h = (__bf16)f;                       // native cvt (RNE on gfx950)
  return __builtin_bit_cast(unsigned short, h);
}
__device__ __forceinline__ float b2f(unsigned short u) {
  unsigned int x = (unsigned int)u << 16;
  return __builtin_bit_cast(float, x);
}
__device__ __forceinline__ unsigned int pk(float lo, float hi) {
  bf2 v = { (__bf16)lo, (__bf16)hi };         // -> v_cvt_pk_bf16_f32
  return __builtin_bit_cast(unsigned int, v);
}
__device__ __forceinline__ bf8 ldsb8(const unsigned short* p) {
  u32x4 u = *(const u32x4*)p;
  return __builtin_bit_cast(bf8, u);
}
__device__ __forceinline__ bf8 as_bf8(u32x4 u) { return __builtin_bit_cast(bf8, u); }
__device__ __forceinline__ f32x4 mfma16(bf8 a, bf8 b, f32x4 c) {
  return __builtin_amdgcn_mfma_f32_16x16x32_bf16(a, b, c, 0, 0, 0);
}
__device__ __forceinline__ bf8 load_w8(const float* p) {   // 8 consecutive f32 -> bf8
  float4 a = ((const float4*)p)[0];
  float4 b = ((const float4*)p)[1];
  u32x4 u = { pk(a.x, a.y), pk(a.z, a.w), pk(b.x, b.y), pk(b.z, b.w) };
  return __builtin_bit_cast(bf8, u);
}
// triangular row index: i s.t. base(i) <= s < base(i+1), base(i)=i*(39-i)/2
__device__ __forceinline__ int tri_row(int s) {
  int i = (int)floorf((39.0f - sqrtf(1521.0f - 8.0f * (float)s)) * 0.5f);
  if (s < i * (39 - i) / 2) --i;
  else if (s >= (i + 1) * (38 - i) / 2) ++i;
  return i;
}

#define FOR12(M)  M(0) M(1) M(2) M(3) M(4) M(5) M(6) M(7) M(8) M(9) M(10) M(11)

__global__ void __launch_bounds__(512)
__attribute__((amdgpu_waves_per_eu(4, 4)))
tri_attn_kernel(const float* __restrict__ x, const float* __restrict__ pos,
                const float* __restrict__ w_in, const float* __restrict__ b_in,
                const float* __restrict__ w_out, const float* __restrict__ b_out,
                const float* __restrict__ ln_g, const float* __restrict__ ln_b,
                float* __restrict__ out)
{
  extern __shared__ char lds[];
  unsigned short* XT = (unsigned short*)(lds + OFF_XT);   // [190][72] x+pos; later Z
  unsigned short* OB = (unsigned short*)(lds + OFF_O);    // [190][72] Q, then O in-place
  unsigned short* VT = (unsigned short*)(lds + OFF_VT);   // [65][196] V^T + ones row

  const int tid  = threadIdx.x;
  const int lane = tid & 63;
  const int wv   = tid >> 6;      // wave = head
  const int q15  = lane & 15;
  const int g    = lane >> 4;
  const int b    = blockIdx.x;
  // (1/sqrt(8)) * log2(e): softmax via exp2, normalization cancels the base swap
  const float qscale = 0.5100694858979282f;

  // ---------------- P0: gather x + pos_emb -> XT (bf16) ----------------
  const float* xb = x + (size_t)b * (361 * 64);
  for (int idx = tid; idx < 3040; idx += 512) {            // 190 rows * 16 float4
    int s = idx >> 4, c = idx & 15;
    int i = tri_row(s);
    int j = i + s - i * (39 - i) / 2;
    float4 v = ((const float4*)(xb + (i * 19 + j) * 64))[c];
    float4 p = ((const float4*)(pos + s * 64))[c];
    u32x2 wd = { pk(v.x + p.x, v.y + p.y), pk(v.z + p.z, v.w + p.w) };
    *(u32x2*)(XT + s * XS + c * 4) = wd;
  }
  if (tid < 64) *(unsigned int*)(VT + tid * VS + 190) = 0u;  // zero VT keys 190,191
  if (tid < 98) ((unsigned int*)(VT + 64 * VS))[tid] = 0x3F803F80u;  // ones row
  __syncthreads();

  // ---------------- P1: projections ----------------
  const int t   = wv >> 1;       // head-pair row-tile (kdims 16t..16t+15)
  const int hh  = wv & 1;        // which half of the pair is my head
  const int nt  = wv & 3;        // Q/V/out-proj n-tile
  const int mtb = wv >> 2;       // Q/V/out-proj m-tile base (0 or 1)
  const bool keep = ((g >> 1) == hh);

  // named K fragments (persistent through P2; V is re-read from LDS)
  #define DECL_K(I) unsigned int k##I##a, k##I##b;
  FOR12(DECL_K)

  // Q = X . W_q^T (normal orientation; C: col=qdim, row=query) -> OB[query][qdim]
  {
    bf8 wq0 = load_w8(w_in + (nt * 16 + q15) * 64 + g * 8);
    bf8 wq1 = load_w8(w_in + (nt * 16 + q15) * 64 + 32 + g * 8);
    float bq = b_in[nt * 16 + q15];
    #pragma unroll
    for (int m6 = 0; m6 < 6; ++m6) {
      int mt = mtb + 2 * m6;
      f32x4 acc = {bq, bq, bq, bq};
      acc = mfma16(ldsb8(XT + (mt * 16 + q15) * XS + g * 8), wq0, acc);
      acc = mfma16(ldsb8(XT + (mt * 16 + q15) * XS + 32 + g * 8), wq1, acc);
      #pragma unroll
      for (int r = 0; r < 4; ++r) {
        int row = mt * 16 + g * 4 + r;
        if (row < 190) OB[row * OS + nt * 16 + q15] = f2b(acc[r] * qscale);
      }
    }
  }

  // K^T = W_k . X^T (C: col=key, row=kdim of the head PAIR). Kept in registers.
  {
    bf8 wk0 = load_w8(w_in + (64 + t * 16 + q15) * 64 + g * 8);
    bf8 wk1 = load_w8(w_in + (64 + t * 16 + q15) * 64 + 32 + g * 8);
    float bk0 = b_in[64 + t * 16 + g * 4 + 0], bk1 = b_in[64 + t * 16 + g * 4 + 1];
    float bk2 = b_in[64 + t * 16 + g * 4 + 2], bk3 = b_in[64 + t * 16 + g * 4 + 3];
    #define KPROJ(I) { \
      f32x4 acc = {0.f, 0.f, 0.f, 0.f}; \
      acc = mfma16(wk0, ldsb8(XT + ((I) * 16 + q15) * XS + g * 8), acc); \
      acc = mfma16(wk1, ldsb8(XT + ((I) * 16 + q15) * XS + 32 + g * 8), acc); \
      k##I##a = pk(acc[0] + bk0, acc[1] + bk1); \
      k##I##b = pk(acc[2] + bk2, acc[3] + bk3); }
    FOR12(KPROJ)
  }

  // V = X . W_v^T (C: col=vdim, row=key) -> VT[dim][key]
  {
    bf8 wv0 = load_w8(w_in + (128 + nt * 16 + q15) * 64 + g * 8);
    bf8 wv1 = load_w8(w_in + (128 + nt * 16 + q15) * 64 + 32 + g * 8);
    float bv = b_in[128 + nt * 16 + q15];
    #pragma unroll
    for (int m6 = 0; m6 < 6; ++m6) {
      int mt = mtb + 2 * m6;
      f32x4 acc = {bv, bv, bv, bv};
      acc = mfma16(ldsb8(XT + (mt * 16 + q15) * XS + g * 8), wv0, acc);
      acc = mfma16(ldsb8(XT + (mt * 16 + q15) * XS + 32 + g * 8), wv1, acc);
      unsigned int w0 = pk(acc[0], acc[1]), w1 = pk(acc[2], acc[3]);
      unsigned short* dst = VT + (nt * 16 + q15) * VS + mt * 16 + g * 4;
      if (mt == 11 && g == 3) {            // keys 188,189 only (190,191 stay 0)
        *(unsigned int*)dst = w0;
      } else {
        u32x2 wd = {w0, w1};
        *(u32x2*)dst = wd;
      }
    }
  }
  __syncthreads();

  // ---------------- P2: attention (K in regs; Q,V from LDS; O in-place) -------
  // Race-free in-place Q->O: wave h writes O only to cols h*8..h*8+7; the only
  // other wave reading those cols (its pair partner) masks them to zero (keep).
  // Softmax denom: A rows 8-15 read the VT ones row -> C row 8 = sum_k P = S.
  const int h = wv;
  const bool mk3 = (g == 3);
  const unsigned short* Vrow = VT + ((q15 < 8) ? (h * 8 + q15) : 64) * VS;

  #define ATT_K(KT, OA) { \
    u32x4 ka = {k##KT##a, k##KT##b, 0u, 0u}; \
    f32x4 sc = mfma16(as_bf8(ka), qb8, f32x4{0.f, 0.f, 0.f, 0.f}); \
    u32x2 vt_ = *(const u32x2*)(Vrow + (KT) * 16 + g * 4); \
    float p0 = __builtin_amdgcn_exp2f(sc[0]); \
    float p1 = __builtin_amdgcn_exp2f(sc[1]); \
    float p2 = __builtin_amdgcn_exp2f(sc[2]); \
    float p3 = __builtin_amdgcn_exp2f(sc[3]); \
    if ((KT) == 11) { p2 = mk3 ? 0.f : p2; p3 = mk3 ? 0.f : p3; } \
    u32x4 pb = {pk(p0, p1), pk(p2, p3), 0u, 0u}; \
    u32x4 aa = {vt_.x, vt_.y, 0u, 0u}; \
    OA = mfma16(as_bf8(aa), as_bf8(pb), OA); }

  #define ATT_MC(MC) { \
    u32x2 uq = *(const u32x2*)(OB + ((MC) * 16 + q15) * OS + t * 16 + g * 4); \
    u32x4 qb = {keep ? uq.x : 0u, keep ? uq.y : 0u, 0u, 0u}; \
    bf8 qb8 = as_bf8(qb); \
    f32x4 o0 = {0.f, 0.f, 0.f, 0.f}, o1 = {0.f, 0.f, 0.f, 0.f}; \
    ATT_K(0, o0)  ATT_K(1, o1)  ATT_K(2, o0)  ATT_K(3, o1) \
    ATT_K(4, o0)  ATT_K(5, o1)  ATT_K(6, o0)  ATT_K(7, o1) \
    ATT_K(8, o0)  ATT_K(9, o1)  ATT_K(10, o0) ATT_K(11, o1) \
    f32x4 o = o0 + o1; \
    float Sv = __shfl(o[0], 32 + q15);        /* C row 8 = S, lanes 32..47 */ \
    float inv = __builtin_amdgcn_rcpf(Sv); \
    int qa = (MC) * 16 + q15; \
    if (g < 2 && qa < 190) { \
      u32x2 wd = { pk(o[0] * inv, o[1] * inv), pk(o[2] * inv, o[3] * inv) }; \
      *(u32x2*)(OB + qa * OS + h * 8 + g * 4) = wd; } }

  FOR12(ATT_MC)
  __syncthreads();

  // ---------------- P3: out-proj + residual (Z in-place into XT) ----------------
  {
    bf8 wo0 = load_w8(w_out + (nt * 16 + q15) * 64 + g * 8);
    bf8 wo1 = load_w8(w_out + (nt * 16 + q15) * 64 + 32 + g * 8);
    float bo = b_out[nt * 16 + q15];
    #pragma unroll
    for (int m6 = 0; m6 < 6; ++m6) {
      int mt = mtb + 2 * m6;
      f32x4 acc = {bo, bo, bo, bo};
      acc = mfma16(ldsb8(OB + (mt * 16 + q15) * OS + g * 8), wo0, acc);
      acc = mfma16(ldsb8(OB + (mt * 16 + q15) * OS + 32 + g * 8), wo1, acc);
      #pragma unroll
      for (int r = 0; r < 4; ++r) {
        int row = mt * 16 + g * 4 + r;
        if (row < 190) {
          int col = nt * 16 + q15;
          float z = acc[r] + b2f(XT[row * XS + col]);
          XT[row * XS + col] = f2b(z);
        }
      }
    }
  }
  __syncthreads();

  // ---------------- P4: LayerNorm + symmetric scatter ----------------
  float gg = ln_g[lane];
  float bb = ln_b[lane];
  float* outb = out + (size_t)b * (361 * 64);
  for (int s = wv; s < 190; s += 8) {
    float zv = b2f(XT[s * XS + lane]);
    float sum = zv;
    #pragma unroll
    for (int m = 1; m < 64; m <<= 1) sum += __shfl_xor(sum, m);
    float mu = sum * 0.015625f;
    float dv = zv - mu;
    float s2 = dv * dv;
    #pragma unroll
    for (int m = 1; m < 64; m <<= 1) s2 += __shfl_xor(s2, m);
    float y = dv * rsqrtf(s2 * 0.015625f + 1e-5f) * gg + bb;
    int i = tri_row(s);
    int j = i + s - i * (39 - i) / 2;
    outb[(i * 19 + j) * 64 + lane] = y;
    outb[(j * 19 + i) * 64 + lane] = y;     // mirror (diagonal rewritten, same value)
  }
}

extern "C" void kernel_launch(void* const* d_in, const int* in_sizes, int n_in,
                              void* d_out, int out_size, void* d_ws, size_t ws_size,
                              hipStream_t stream) {
  const float* x     = (const float*)d_in[0];
  const float* pos   = (const float*)d_in[1];
  const float* w_in  = (const float*)d_in[2];
  const float* b_in  = (const float*)d_in[3];
  const float* w_out = (const float*)d_in[4];
  const float* b_out = (const float*)d_in[5];
  const float* ln_g  = (const float*)d_in[6];
  const float* ln_b  = (const float*)d_in[7];
  float* out = (float*)d_out;
  (void)in_sizes; (void)n_in; (void)out_size; (void)d_ws; (void)ws_size;
  hipFuncSetAttribute((const void*)tri_attn_kernel,
                      hipFuncAttributeMaxDynamicSharedMemorySize, LDS_BYTES);
  tri_attn_kernel<<<4096, 512, LDS_BYTES, stream>>>(x, pos, w_in, b_in, w_out,
                                                    b_out, ln_g, ln_b, out);
}

// Round 12
// 348.567 us; speedup vs baseline: 1.6611x; 1.0815x over previous
//
#include <hip/hip_runtime.h>
#include <hip/hip_bf16.h>

// ---------------------------------------------------------------------------
// TriangularSelfAttention fused kernel (round 12 = round 9 base + K=16 MFMA).
// One block per batch (4096 blocks), 512 threads = 8 waves, LDS = 80.2 KB
// (2 blocks/CU). Round-12 change vs round 9 (the last passing kernel):
//  P2's QK^T and PV MFMAs switch 16x16x32 -> 16x16x16 (v_mfma_f32_16x16x16
//  bf16_1k): A/B = 4 bf16 = exactly our fragment size. Removes all zero-slot
//  padding (3 u32x4 builds with zero halves per ATT_K ~ 6-8 v_mov each).
//  Contraction pairs A(g,slot) with B(g,slot); both operands place logical
//  kdim/key g*4+s at slot s, so the HW (g,slot)->k map cancels (same
//  invariance proven by rounds 1-9 on slots 0-3).
// P4 = round 9's proven 64-lane LN (the 16-lane rewrite failed twice; parked).
// ---------------------------------------------------------------------------

typedef __bf16 bf8 __attribute__((ext_vector_type(8)));
typedef __bf16 bf2 __attribute__((ext_vector_type(2)));
typedef short s16x4 __attribute__((ext_vector_type(4)));
typedef float f32x4 __attribute__((ext_vector_type(4)));
typedef unsigned int u32x4 __attribute__((ext_vector_type(4)));
typedef unsigned int u32x2 __attribute__((ext_vector_type(2)));

#define LDS_BYTES 80200
#define OFF_XT 0
#define OFF_O  27360
#define OFF_VT 54720
#define XS 72     // XT row stride (elements)
#define OS 72     // O/Q row stride
#define VS 196    // VT row stride (rows 0..63 = v dims, row 64 = ones)

__device__ __forceinline__ unsigned short f2b(float f) {
  __bf16 h = (__bf16)f;                       // native cvt
  return __builtin_bit_cast(unsigned short, h);
}
__device__ __forceinline__ float b2f(unsigned short u) {
  unsigned int x = (unsigned int)u << 16;
  return __builtin_bit_cast(float, x);
}
__device__ __forceinline__ unsigned int pk(float lo, float hi) {
  bf2 v = { (__bf16)lo, (__bf16)hi };         // -> v_cvt_pk_bf16_f32
  return __builtin_bit_cast(unsigned int, v);
}
__device__ __forceinline__ bf8 ldsb8(const unsigned short* p) {
  u32x4 u = *(const u32x4*)p;
  return __builtin_bit_cast(bf8, u);
}
__device__ __forceinline__ s16x4 as_bf4(u32x2 u) { return __builtin_bit_cast(s16x4, u); }
__device__ __forceinline__ f32x4 mfma16(bf8 a, bf8 b, f32x4 c) {
  return __builtin_amdgcn_mfma_f32_16x16x32_bf16(a, b, c, 0, 0, 0);
}
__device__ __forceinline__ f32x4 mfma16k(s16x4 a, s16x4 b, f32x4 c) {
  return __builtin_amdgcn_mfma_f32_16x16x16bf16_1k(a, b, c, 0, 0, 0);
}
__device__ __forceinline__ bf8 load_w8(const float* p) {   // 8 consecutive f32 -> bf8
  float4 a = ((const float4*)p)[0];
  float4 b = ((const float4*)p)[1];
  u32x4 u = { pk(a.x, a.y), pk(a.z, a.w), pk(b.x, b.y), pk(b.z, b.w) };
  return __builtin_bit_cast(bf8, u);
}
// triangular row index: i s.t. base(i) <= s < base(i+1), base(i)=i*(39-i)/2
__device__ __forceinline__ int tri_row(int s) {
  int i = (int)floorf((39.0f - sqrtf(1521.0f - 8.0f * (float)s)) * 0.5f);
  if (s < i * (39 - i) / 2) --i;
  else if (s >= (i + 1) * (38 - i) / 2) ++i;
  return i;
}

#define FOR12(M)  M(0) M(1) M(2) M(3) M(4) M(5) M(6) M(7) M(8) M(9) M(10) M(11)

__global__ void __launch_bounds__(512)
__attribute__((amdgpu_waves_per_eu(4, 4)))
tri_attn_kernel(const float* __restrict__ x, const float* __restrict__ pos,
                const float* __restrict__ w_in, const float* __restrict__ b_in,
                const float* __restrict__ w_out, const float* __restrict__ b_out,
                const float* __restrict__ ln_g, const float* __restrict__ ln_b,
                float* __restrict__ out)
{
  extern __shared__ char lds[];
  unsigned short* XT = (unsigned short*)(lds + OFF_XT);   // [190][72] x+pos; later Z
  unsigned short* OB = (unsigned short*)(lds + OFF_O);    // [190][72] Q, then O in-place
  unsigned short* VT = (unsigned short*)(lds + OFF_VT);   // [65][196] V^T + ones row

  const int tid  = threadIdx.x;
  const int lane = tid & 63;
  const int wv   = tid >> 6;      // wave = head
  const int q15  = lane & 15;
  const int g    = lane >> 4;
  const int b    = blockIdx.x;
  // (1/sqrt(8)) * log2(e): softmax via exp2, normalization cancels the base swap
  const float qscale = 0.5100694858979282f;

  // ---------------- P0: gather x + pos_emb -> XT (bf16) ----------------
  const float* xb = x + (size_t)b * (361 * 64);
  for (int idx = tid; idx < 3040; idx += 512) {            // 190 rows * 16 float4
    int s = idx >> 4, c = idx & 15;
    int i = tri_row(s);
    int j = i + s - i * (39 - i) / 2;
    float4 v = ((const float4*)(xb + (i * 19 + j) * 64))[c];
    float4 p = ((const float4*)(pos + s * 64))[c];
    u32x2 wd = { pk(v.x + p.x, v.y + p.y), pk(v.z + p.z, v.w + p.w) };
    *(u32x2*)(XT + s * XS + c * 4) = wd;
  }
  if (tid < 64) *(unsigned int*)(VT + tid * VS + 190) = 0u;  // zero VT keys 190,191
  if (tid < 98) ((unsigned int*)(VT + 64 * VS))[tid] = 0x3F803F80u;  // ones row
  __syncthreads();

  // ---------------- P1: projections ----------------
  const int t   = wv >> 1;       // head-pair row-tile (kdims 16t..16t+15)
  const int hh  = wv & 1;        // which half of the pair is my head
  const int nt  = wv & 3;        // Q/V/out-proj n-tile
  const int mtb = wv >> 2;       // Q/V/out-proj m-tile base (0 or 1)
  const bool keep = ((g >> 1) == hh);

  // named K fragments (persistent through P2; V is re-read from LDS)
  #define DECL_K(I) unsigned int k##I##a, k##I##b;
  FOR12(DECL_K)

  // Q = X . W_q^T (normal orientation; C: col=qdim, row=query) -> OB[query][qdim]
  {
    bf8 wq0 = load_w8(w_in + (nt * 16 + q15) * 64 + g * 8);
    bf8 wq1 = load_w8(w_in + (nt * 16 + q15) * 64 + 32 + g * 8);
    float bq = b_in[nt * 16 + q15];
    #pragma unroll
    for (int m6 = 0; m6 < 6; ++m6) {
      int mt = mtb + 2 * m6;
      f32x4 acc = {bq, bq, bq, bq};
      acc = mfma16(ldsb8(XT + (mt * 16 + q15) * XS + g * 8), wq0, acc);
      acc = mfma16(ldsb8(XT + (mt * 16 + q15) * XS + 32 + g * 8), wq1, acc);
      #pragma unroll
      for (int r = 0; r < 4; ++r) {
        int row = mt * 16 + g * 4 + r;
        if (row < 190) OB[row * OS + nt * 16 + q15] = f2b(acc[r] * qscale);
      }
    }
  }

  // K^T = W_k . X^T (C: col=key, row=kdim of the head PAIR). Kept in registers.
  {
    bf8 wk0 = load_w8(w_in + (64 + t * 16 + q15) * 64 + g * 8);
    bf8 wk1 = load_w8(w_in + (64 + t * 16 + q15) * 64 + 32 + g * 8);
    float bk0 = b_in[64 + t * 16 + g * 4 + 0], bk1 = b_in[64 + t * 16 + g * 4 + 1];
    float bk2 = b_in[64 + t * 16 + g * 4 + 2], bk3 = b_in[64 + t * 16 + g * 4 + 3];
    #define KPROJ(I) { \
      f32x4 acc = {0.f, 0.f, 0.f, 0.f}; \
      acc = mfma16(wk0, ldsb8(XT + ((I) * 16 + q15) * XS + g * 8), acc); \
      acc = mfma16(wk1, ldsb8(XT + ((I) * 16 + q15) * XS + 32 + g * 8), acc); \
      k##I##a = pk(acc[0] + bk0, acc[1] + bk1); \
      k##I##b = pk(acc[2] + bk2, acc[3] + bk3); }
    FOR12(KPROJ)
  }

  // V = X . W_v^T (C: col=vdim, row=key) -> VT[dim][key]
  {
    bf8 wv0 = load_w8(w_in + (128 + nt * 16 + q15) * 64 + g * 8);
    bf8 wv1 = load_w8(w_in + (128 + nt * 16 + q15) * 64 + 32 + g * 8);
    float bv = b_in[128 + nt * 16 + q15];
    #pragma unroll
    for (int m6 = 0; m6 < 6; ++m6) {
      int mt = mtb + 2 * m6;
      f32x4 acc = {bv, bv, bv, bv};
      acc = mfma16(ldsb8(XT + (mt * 16 + q15) * XS + g * 8), wv0, acc);
      acc = mfma16(ldsb8(XT + (mt * 16 + q15) * XS + 32 + g * 8), wv1, acc);
      unsigned int w0 = pk(acc[0], acc[1]), w1 = pk(acc[2], acc[3]);
      unsigned short* dst = VT + (nt * 16 + q15) * VS + mt * 16 + g * 4;
      if (mt == 11 && g == 3) {            // keys 188,189 only (190,191 stay 0)
        *(unsigned int*)dst = w0;
      } else {
        u32x2 wd = {w0, w1};
        *(u32x2*)dst = wd;
      }
    }
  }
  __syncthreads();

  // ---------------- P2: attention (K in regs; Q,V from LDS; O in-place) -------
  // Race-free in-place Q->O: wave h writes O only to cols h*8..h*8+7; the only
  // other wave reading those cols (its pair partner) masks them to zero (keep).
  // Softmax denom: A rows 8-15 read the VT ones row -> C rows >=8 = sum_k P = S.
  // All MFMAs here are 16x16x16 (K=16 = exactly our fragments; no padding).
  const int h = wv;
  const bool mk3 = (g == 3);
  const unsigned short* Vrow = VT + ((q15 < 8) ? (h * 8 + q15) : 64) * VS;

  #define ATT_K(KT, OA) { \
    u32x2 ka = {k##KT##a, k##KT##b}; \
    f32x4 sc = mfma16k(as_bf4(ka), qb4, f32x4{0.f, 0.f, 0.f, 0.f}); \
    u32x2 vt_ = *(const u32x2*)(Vrow + (KT) * 16 + g * 4); \
    float p0 = __builtin_amdgcn_exp2f(sc[0]); \
    float p1 = __builtin_amdgcn_exp2f(sc[1]); \
    float p2 = __builtin_amdgcn_exp2f(sc[2]); \
    float p3 = __builtin_amdgcn_exp2f(sc[3]); \
    if ((KT) == 11) { p2 = mk3 ? 0.f : p2; p3 = mk3 ? 0.f : p3; } \
    u32x2 pb = {pk(p0, p1), pk(p2, p3)}; \
    OA = mfma16k(as_bf4(vt_), as_bf4(pb), OA); }

  #define ATT_MC(MC) { \
    u32x2 uq = *(const u32x2*)(OB + ((MC) * 16 + q15) * OS + t * 16 + g * 4); \
    u32x2 qb = {keep ? uq.x : 0u, keep ? uq.y : 0u}; \
    s16x4 qb4 = as_bf4(qb); \
    f32x4 o0 = {0.f, 0.f, 0.f, 0.f}, o1 = {0.f, 0.f, 0.f, 0.f}; \
    ATT_K(0, o0)  ATT_K(1, o1)  ATT_K(2, o0)  ATT_K(3, o1) \
    ATT_K(4, o0)  ATT_K(5, o1)  ATT_K(6, o0)  ATT_K(7, o1) \
    ATT_K(8, o0)  ATT_K(9, o1)  ATT_K(10, o0) ATT_K(11, o1) \
    f32x4 o = o0 + o1; \
    float Sv = __shfl(o[0], 32 + q15);        /* C row 8 = S, lanes 32..47 */ \
    float inv = __builtin_amdgcn_rcpf(Sv); \
    int qa = (MC) * 16 + q15; \
    if (g < 2 && qa < 190) { \
      u32x2 wd = { pk(o[0] * inv, o[1] * inv), pk(o[2] * inv, o[3] * inv) }; \
      *(u32x2*)(OB + qa * OS + h * 8 + g * 4) = wd; } }

  FOR12(ATT_MC)
  __syncthreads();

  // ---------------- P3: out-proj + residual (Z in-place into XT) ----------------
  {
    bf8 wo0 = load_w8(w_out + (nt * 16 + q15) * 64 + g * 8);
    bf8 wo1 = load_w8(w_out + (nt * 16 + q15) * 64 + 32 + g * 8);
    float bo = b_out[nt * 16 + q15];
    #pragma unroll
    for (int m6 = 0; m6 < 6; ++m6) {
      int mt = mtb + 2 * m6;
      f32x4 acc = {bo, bo, bo, bo};
      acc = mfma16(ldsb8(OB + (mt * 16 + q15) * OS + g * 8), wo0, acc);
      acc = mfma16(ldsb8(OB + (mt * 16 + q15) * OS + 32 + g * 8), wo1, acc);
      #pragma unroll
      for (int r = 0; r < 4; ++r) {
        int row = mt * 16 + g * 4 + r;
        if (row < 190) {
          int col = nt * 16 + q15;
          float z = acc[r] + b2f(XT[row * XS + col]);
          XT[row * XS + col] = f2b(z);
        }
      }
    }
  }
  __syncthreads();

  // ---------------- P4: LayerNorm + symmetric scatter (round-9 proven form) ----
  float gg = ln_g[lane];
  float bb = ln_b[lane];
  float* outb = out + (size_t)b * (361 * 64);
  for (int s = wv; s < 190; s += 8) {
    float zv = b2f(XT[s * XS + lane]);
    float sum = zv;
    #pragma unroll
    for (int m = 1; m < 64; m <<= 1) sum += __shfl_xor(sum, m);
    float mu = sum * 0.015625f;
    float dv = zv - mu;
    float s2 = dv * dv;
    #pragma unroll
    for (int m = 1; m < 64; m <<= 1) s2 += __shfl_xor(s2, m);
    float y = dv * rsqrtf(s2 * 0.015625f + 1e-5f) * gg + bb;
    int i = tri_row(s);
    int j = i + s - i * (39 - i) / 2;
    outb[(i * 19 + j) * 64 + lane] = y;
    outb[(j * 19 + i) * 64 + lane] = y;     // mirror (diagonal rewritten, same value)
  }
}

extern "C" void kernel_launch(void* const* d_in, const int* in_sizes, int n_in,
                              void* d_out, int out_size, void* d_ws, size_t ws_size,
                              hipStream_t stream) {
  const float* x     = (const float*)d_in[0];
  const float* pos   = (const float*)d_in[1];
  const float* w_in  = (const float*)d_in[2];
  const float* b_in  = (const float*)d_in[3];
  const float* w_out = (const float*)d_in[4];
  const float* b_out = (const float*)d_in[5];
  const float* ln_g  = (const float*)d_in[6];
  const float* ln_b  = (const float*)d_in[7];
  float* out = (float*)d_out;
  (void)in_sizes; (void)n_in; (void)out_size; (void)d_ws; (void)ws_size;
  hipFuncSetAttribute((const void*)tri_attn_kernel,
                      hipFuncAttributeMaxDynamicSharedMemorySize, LDS_BYTES);
  tri_attn_kernel<<<4096, 512, LDS_BYTES, stream>>>(x, pos, w_in, b_in, w_out,
                                                    b_out, ln_g, ln_b, out);
}

// Round 13
// 303.286 us; speedup vs baseline: 1.9091x; 1.1493x over previous
//
#include <hip/hip_runtime.h>
#include <hip/hip_bf16.h>

// ---------------------------------------------------------------------------
// TriangularSelfAttention fused kernel (round 13 = round 12 + MFMA LayerNorm).
// One block per batch (4096 blocks), 512 threads = 8 waves, LDS = 80.2 KB
// (2 blocks/CU). Round-13 change vs round 12 (passing, 349 us):
//  P4 LayerNorm statistics via MFMA with B=ones (D[m][n] = sum_k A[m,k] --
//  slot->k bijection cancels, layout HW-proven by round 12's P2): waves 0-5
//  compute per-row sum and sumsq of Z, lanes q15==0 write {mu, rsqrt(var)}
//  into the dead VT region; apply phase is shuffle-free. Removes 288
//  full-wave ds_swizzle shuffles + ~300 VALU per wave.
// ---------------------------------------------------------------------------

typedef __bf16 bf8 __attribute__((ext_vector_type(8)));
typedef __bf16 bf2 __attribute__((ext_vector_type(2)));
typedef short s16x4 __attribute__((ext_vector_type(4)));
typedef float f32x4 __attribute__((ext_vector_type(4)));
typedef unsigned int u32x4 __attribute__((ext_vector_type(4)));
typedef unsigned int u32x2 __attribute__((ext_vector_type(2)));

#define LDS_BYTES 80200
#define OFF_XT 0
#define OFF_O  27360
#define OFF_VT 54720
#define XS 72     // XT row stride (elements)
#define OS 72     // O/Q row stride
#define VS 196    // VT row stride (rows 0..63 = v dims, row 64 = ones)

__device__ __forceinline__ unsigned short f2b(float f) {
  __bf16 h = (__bf16)f;                       // native cvt
  return __builtin_bit_cast(unsigned short, h);
}
__device__ __forceinline__ float b2f(unsigned short u) {
  unsigned int x = (unsigned int)u << 16;
  return __builtin_bit_cast(float, x);
}
__device__ __forceinline__ float b2f_lo(unsigned int u) {
  return __builtin_bit_cast(float, u << 16);
}
__device__ __forceinline__ float b2f_hi(unsigned int u) {
  return __builtin_bit_cast(float, u & 0xFFFF0000u);
}
__device__ __forceinline__ unsigned int pk(float lo, float hi) {
  bf2 v = { (__bf16)lo, (__bf16)hi };         // -> v_cvt_pk_bf16_f32
  return __builtin_bit_cast(unsigned int, v);
}
__device__ __forceinline__ bf8 ldsb8(const unsigned short* p) {
  u32x4 u = *(const u32x4*)p;
  return __builtin_bit_cast(bf8, u);
}
__device__ __forceinline__ s16x4 as_bf4(u32x2 u) { return __builtin_bit_cast(s16x4, u); }
__device__ __forceinline__ f32x4 mfma16(bf8 a, bf8 b, f32x4 c) {
  return __builtin_amdgcn_mfma_f32_16x16x32_bf16(a, b, c, 0, 0, 0);
}
__device__ __forceinline__ f32x4 mfma16k(s16x4 a, s16x4 b, f32x4 c) {
  return __builtin_amdgcn_mfma_f32_16x16x16bf16_1k(a, b, c, 0, 0, 0);
}
__device__ __forceinline__ bf8 load_w8(const float* p) {   // 8 consecutive f32 -> bf8
  float4 a = ((const float4*)p)[0];
  float4 b = ((const float4*)p)[1];
  u32x4 u = { pk(a.x, a.y), pk(a.z, a.w), pk(b.x, b.y), pk(b.z, b.w) };
  return __builtin_bit_cast(bf8, u);
}
// triangular row index: i s.t. base(i) <= s < base(i+1), base(i)=i*(39-i)/2
__device__ __forceinline__ int tri_row(int s) {
  int i = (int)floorf((39.0f - sqrtf(1521.0f - 8.0f * (float)s)) * 0.5f);
  if (s < i * (39 - i) / 2) --i;
  else if (s >= (i + 1) * (38 - i) / 2) ++i;
  return i;
}

#define FOR12(M)  M(0) M(1) M(2) M(3) M(4) M(5) M(6) M(7) M(8) M(9) M(10) M(11)

__global__ void __launch_bounds__(512)
__attribute__((amdgpu_waves_per_eu(4, 4)))
tri_attn_kernel(const float* __restrict__ x, const float* __restrict__ pos,
                const float* __restrict__ w_in, const float* __restrict__ b_in,
                const float* __restrict__ w_out, const float* __restrict__ b_out,
                const float* __restrict__ ln_g, const float* __restrict__ ln_b,
                float* __restrict__ out)
{
  extern __shared__ char lds[];
  unsigned short* XT = (unsigned short*)(lds + OFF_XT);   // [190][72] x+pos; later Z
  unsigned short* OB = (unsigned short*)(lds + OFF_O);    // [190][72] Q, then O in-place
  unsigned short* VT = (unsigned short*)(lds + OFF_VT);   // [65][196] V^T + ones row

  const int tid  = threadIdx.x;
  const int lane = tid & 63;
  const int wv   = tid >> 6;      // wave = head
  const int q15  = lane & 15;
  const int g    = lane >> 4;
  const int b    = blockIdx.x;
  // (1/sqrt(8)) * log2(e): softmax via exp2, normalization cancels the base swap
  const float qscale = 0.5100694858979282f;

  // ---------------- P0: gather x + pos_emb -> XT (bf16) ----------------
  const float* xb = x + (size_t)b * (361 * 64);
  for (int idx = tid; idx < 3040; idx += 512) {            // 190 rows * 16 float4
    int s = idx >> 4, c = idx & 15;
    int i = tri_row(s);
    int j = i + s - i * (39 - i) / 2;
    float4 v = ((const float4*)(xb + (i * 19 + j) * 64))[c];
    float4 p = ((const float4*)(pos + s * 64))[c];
    u32x2 wd = { pk(v.x + p.x, v.y + p.y), pk(v.z + p.z, v.w + p.w) };
    *(u32x2*)(XT + s * XS + c * 4) = wd;
  }
  if (tid < 64) *(unsigned int*)(VT + tid * VS + 190) = 0u;  // zero VT keys 190,191
  if (tid < 98) ((unsigned int*)(VT + 64 * VS))[tid] = 0x3F803F80u;  // ones row
  __syncthreads();

  // ---------------- P1: projections ----------------
  const int t   = wv >> 1;       // head-pair row-tile (kdims 16t..16t+15)
  const int hh  = wv & 1;        // which half of the pair is my head
  const int nt  = wv & 3;        // Q/V/out-proj n-tile
  const int mtb = wv >> 2;       // Q/V/out-proj m-tile base (0 or 1)
  const bool keep = ((g >> 1) == hh);

  // named K fragments (persistent through P2; V is re-read from LDS)
  #define DECL_K(I) unsigned int k##I##a, k##I##b;
  FOR12(DECL_K)

  // Q = X . W_q^T (normal orientation; C: col=qdim, row=query) -> OB[query][qdim]
  {
    bf8 wq0 = load_w8(w_in + (nt * 16 + q15) * 64 + g * 8);
    bf8 wq1 = load_w8(w_in + (nt * 16 + q15) * 64 + 32 + g * 8);
    float bq = b_in[nt * 16 + q15];
    #pragma unroll
    for (int m6 = 0; m6 < 6; ++m6) {
      int mt = mtb + 2 * m6;
      f32x4 acc = {bq, bq, bq, bq};
      acc = mfma16(ldsb8(XT + (mt * 16 + q15) * XS + g * 8), wq0, acc);
      acc = mfma16(ldsb8(XT + (mt * 16 + q15) * XS + 32 + g * 8), wq1, acc);
      #pragma unroll
      for (int r = 0; r < 4; ++r) {
        int row = mt * 16 + g * 4 + r;
        if (row < 190) OB[row * OS + nt * 16 + q15] = f2b(acc[r] * qscale);
      }
    }
  }

  // K^T = W_k . X^T (C: col=key, row=kdim of the head PAIR). Kept in registers.
  {
    bf8 wk0 = load_w8(w_in + (64 + t * 16 + q15) * 64 + g * 8);
    bf8 wk1 = load_w8(w_in + (64 + t * 16 + q15) * 64 + 32 + g * 8);
    float bk0 = b_in[64 + t * 16 + g * 4 + 0], bk1 = b_in[64 + t * 16 + g * 4 + 1];
    float bk2 = b_in[64 + t * 16 + g * 4 + 2], bk3 = b_in[64 + t * 16 + g * 4 + 3];
    #define KPROJ(I) { \
      f32x4 acc = {0.f, 0.f, 0.f, 0.f}; \
      acc = mfma16(wk0, ldsb8(XT + ((I) * 16 + q15) * XS + g * 8), acc); \
      acc = mfma16(wk1, ldsb8(XT + ((I) * 16 + q15) * XS + 32 + g * 8), acc); \
      k##I##a = pk(acc[0] + bk0, acc[1] + bk1); \
      k##I##b = pk(acc[2] + bk2, acc[3] + bk3); }
    FOR12(KPROJ)
  }

  // V = X . W_v^T (C: col=vdim, row=key) -> VT[dim][key]
  {
    bf8 wv0 = load_w8(w_in + (128 + nt * 16 + q15) * 64 + g * 8);
    bf8 wv1 = load_w8(w_in + (128 + nt * 16 + q15) * 64 + 32 + g * 8);
    float bv = b_in[128 + nt * 16 + q15];
    #pragma unroll
    for (int m6 = 0; m6 < 6; ++m6) {
      int mt = mtb + 2 * m6;
      f32x4 acc = {bv, bv, bv, bv};
      acc = mfma16(ldsb8(XT + (mt * 16 + q15) * XS + g * 8), wv0, acc);
      acc = mfma16(ldsb8(XT + (mt * 16 + q15) * XS + 32 + g * 8), wv1, acc);
      unsigned int w0 = pk(acc[0], acc[1]), w1 = pk(acc[2], acc[3]);
      unsigned short* dst = VT + (nt * 16 + q15) * VS + mt * 16 + g * 4;
      if (mt == 11 && g == 3) {            // keys 188,189 only (190,191 stay 0)
        *(unsigned int*)dst = w0;
      } else {
        u32x2 wd = {w0, w1};
        *(u32x2*)dst = wd;
      }
    }
  }
  __syncthreads();

  // ---------------- P2: attention (K in regs; Q,V from LDS; O in-place) -------
  // Race-free in-place Q->O: wave h writes O only to cols h*8..h*8+7; the only
  // other wave reading those cols (its pair partner) masks them to zero (keep).
  // Softmax denom: A rows 8-15 read the VT ones row -> C rows >=8 = sum_k P = S.
  // All MFMAs here are 16x16x16 (K=16 = exactly our fragments; no padding).
  const int h = wv;
  const bool mk3 = (g == 3);
  const unsigned short* Vrow = VT + ((q15 < 8) ? (h * 8 + q15) : 64) * VS;

  #define ATT_K(KT, OA) { \
    u32x2 ka = {k##KT##a, k##KT##b}; \
    f32x4 sc = mfma16k(as_bf4(ka), qb4, f32x4{0.f, 0.f, 0.f, 0.f}); \
    u32x2 vt_ = *(const u32x2*)(Vrow + (KT) * 16 + g * 4); \
    float p0 = __builtin_amdgcn_exp2f(sc[0]); \
    float p1 = __builtin_amdgcn_exp2f(sc[1]); \
    float p2 = __builtin_amdgcn_exp2f(sc[2]); \
    float p3 = __builtin_amdgcn_exp2f(sc[3]); \
    if ((KT) == 11) { p2 = mk3 ? 0.f : p2; p3 = mk3 ? 0.f : p3; } \
    u32x2 pb = {pk(p0, p1), pk(p2, p3)}; \
    OA = mfma16k(as_bf4(vt_), as_bf4(pb), OA); }

  #define ATT_MC(MC) { \
    u32x2 uq = *(const u32x2*)(OB + ((MC) * 16 + q15) * OS + t * 16 + g * 4); \
    u32x2 qb = {keep ? uq.x : 0u, keep ? uq.y : 0u}; \
    s16x4 qb4 = as_bf4(qb); \
    f32x4 o0 = {0.f, 0.f, 0.f, 0.f}, o1 = {0.f, 0.f, 0.f, 0.f}; \
    ATT_K(0, o0)  ATT_K(1, o1)  ATT_K(2, o0)  ATT_K(3, o1) \
    ATT_K(4, o0)  ATT_K(5, o1)  ATT_K(6, o0)  ATT_K(7, o1) \
    ATT_K(8, o0)  ATT_K(9, o1)  ATT_K(10, o0) ATT_K(11, o1) \
    f32x4 o = o0 + o1; \
    float Sv = __shfl(o[0], 32 + q15);        /* C row 8 = S, lanes 32..47 */ \
    float inv = __builtin_amdgcn_rcpf(Sv); \
    int qa = (MC) * 16 + q15; \
    if (g < 2 && qa < 190) { \
      u32x2 wd = { pk(o[0] * inv, o[1] * inv), pk(o[2] * inv, o[3] * inv) }; \
      *(u32x2*)(OB + qa * OS + h * 8 + g * 4) = wd; } }

  FOR12(ATT_MC)
  __syncthreads();

  // ---------------- P3: out-proj + residual (Z in-place into XT) ----------------
  {
    bf8 wo0 = load_w8(w_out + (nt * 16 + q15) * 64 + g * 8);
    bf8 wo1 = load_w8(w_out + (nt * 16 + q15) * 64 + 32 + g * 8);
    float bo = b_out[nt * 16 + q15];
    #pragma unroll
    for (int m6 = 0; m6 < 6; ++m6) {
      int mt = mtb + 2 * m6;
      f32x4 acc = {bo, bo, bo, bo};
      acc = mfma16(ldsb8(OB + (mt * 16 + q15) * OS + g * 8), wo0, acc);
      acc = mfma16(ldsb8(OB + (mt * 16 + q15) * OS + 32 + g * 8), wo1, acc);
      #pragma unroll
      for (int r = 0; r < 4; ++r) {
        int row = mt * 16 + g * 4 + r;
        if (row < 190) {
          int col = nt * 16 + q15;
          float z = acc[r] + b2f(XT[row * XS + col]);
          XT[row * XS + col] = f2b(z);
        }
      }
    }
  }
  __syncthreads();

  // ---------------- P4a: LN statistics via MFMA (B = ones) ----------------
  // D[m][n] = sum_k A[m,k] * 1 -- slot->k bijection cancels with B=ones.
  // Waves 0-5: tiles wv and wv+6. A: lane q15 = row, slots = dims c*16+g*4..+3.
  // C (m89, round-12-proven): row = g*4+r, col = q15 -> lanes q15==0 write stats.
  float* MU = (float*)(lds + OFF_VT);          // reuse dead VT region: [190][2] {mu, rs}
  if (wv < 6) {
    const s16x4 ones4 = { (short)0x3F80, (short)0x3F80, (short)0x3F80, (short)0x3F80 };
    #pragma unroll
    for (int half = 0; half < 2; ++half) {
      int s0 = (wv + half * 6) * 16;
      f32x4 cs = {0.f, 0.f, 0.f, 0.f};
      f32x4 cq = {0.f, 0.f, 0.f, 0.f};
      #pragma unroll
      for (int c = 0; c < 4; ++c) {
        u32x2 zz = *(const u32x2*)(XT + (s0 + q15) * XS + c * 16 + g * 4);
        cs = mfma16k(as_bf4(zz), ones4, cs);
        float f0 = b2f_lo(zz.x), f1 = b2f_hi(zz.x);
        float f2 = b2f_lo(zz.y), f3 = b2f_hi(zz.y);
        u32x2 qq = { pk(f0 * f0, f1 * f1), pk(f2 * f2, f3 * f3) };
        cq = mfma16k(as_bf4(qq), ones4, cq);
      }
      if (q15 == 0) {
        #pragma unroll
        for (int r = 0; r < 4; ++r) {
          int row = s0 + g * 4 + r;
          if (row < 190) {
            float mu = cs[r] * 0.015625f;
            float var = cq[r] * 0.015625f - mu * mu;
            float2 mr = { mu, rsqrtf(var + 1e-5f) };
            *(float2*)(MU + row * 2) = mr;
          }
        }
      }
    }
  }
  __syncthreads();

  // ---------------- P4b: normalize + symmetric scatter (shuffle-free) ---------
  {
    float gg = ln_g[lane];
    float bb = ln_b[lane];
    float* outb = out + (size_t)b * (361 * 64);
    for (int s = wv; s < 190; s += 8) {
      float2 mr = *(const float2*)(MU + s * 2);     // broadcast read (same addr)
      float zv = b2f(XT[s * XS + lane]);
      float y = (zv - mr.x) * mr.y * gg + bb;
      int i = tri_row(s);
      int j = i + s - i * (39 - i) / 2;
      outb[(i * 19 + j) * 64 + lane] = y;
      outb[(j * 19 + i) * 64 + lane] = y;           // mirror (diagonal: same value)
    }
  }
}

extern "C" void kernel_launch(void* const* d_in, const int* in_sizes, int n_in,
                              void* d_out, int out_size, void* d_ws, size_t ws_size,
                              hipStream_t stream) {
  const float* x     = (const float*)d_in[0];
  const float* pos   = (const float*)d_in[1];
  const float* w_in  = (const float*)d_in[2];
  const float* b_in  = (const float*)d_in[3];
  const float* w_out = (const float*)d_in[4];
  const float* b_out = (const float*)d_in[5];
  const float* ln_g  = (const float*)d_in[6];
  const float* ln_b  = (const float*)d_in[7];
  float* out = (float*)d_out;
  (void)in_sizes; (void)n_in; (void)out_size; (void)d_ws; (void)ws_size;
  hipFuncSetAttribute((const void*)tri_attn_kernel,
                      hipFuncAttributeMaxDynamicSharedMemorySize, LDS_BYTES);
  tri_attn_kernel<<<4096, 512, LDS_BYTES, stream>>>(x, pos, w_in, b_in, w_out,
                                                    b_out, ln_g, ln_b, out);
}

// Round 14
// 299.888 us; speedup vs baseline: 1.9308x; 1.0113x over previous
//
#include <hip/hip_runtime.h>
#include <hip/hip_bf16.h>

// ---------------------------------------------------------------------------
// TriangularSelfAttention fused kernel (round 14 = round 13 + V reg cache).
// One block per batch (4096 blocks), 512 threads = 8 waves, LDS = 80.2 KB
// (2 blocks/CU). Round-14 change vs round 13 (passing, 303 us):
//  P2's V fragments (chunk-invariant) hoisted into 24 named registers --
//  removes 144 ds_read_b64 + addressing per wave. Re-test of the round-8
//  revert now that VGPR pressure is low (56 used, cap 128, zero spills).
//  Tripwire: WRITE_SIZE must stay at exactly the 369 MB output; any jump
//  means allocator spill -> revert.
// ---------------------------------------------------------------------------

typedef __bf16 bf8 __attribute__((ext_vector_type(8)));
typedef __bf16 bf2 __attribute__((ext_vector_type(2)));
typedef short s16x4 __attribute__((ext_vector_type(4)));
typedef float f32x4 __attribute__((ext_vector_type(4)));
typedef unsigned int u32x4 __attribute__((ext_vector_type(4)));
typedef unsigned int u32x2 __attribute__((ext_vector_type(2)));

#define LDS_BYTES 80200
#define OFF_XT 0
#define OFF_O  27360
#define OFF_VT 54720
#define XS 72     // XT row stride (elements)
#define OS 72     // O/Q row stride
#define VS 196    // VT row stride (rows 0..63 = v dims, row 64 = ones)

__device__ __forceinline__ unsigned short f2b(float f) {
  __bf16 h = (__bf16)f;                       // native cvt
  return __builtin_bit_cast(unsigned short, h);
}
__device__ __forceinline__ float b2f(unsigned short u) {
  unsigned int x = (unsigned int)u << 16;
  return __builtin_bit_cast(float, x);
}
__device__ __forceinline__ float b2f_lo(unsigned int u) {
  return __builtin_bit_cast(float, u << 16);
}
__device__ __forceinline__ float b2f_hi(unsigned int u) {
  return __builtin_bit_cast(float, u & 0xFFFF0000u);
}
__device__ __forceinline__ unsigned int pk(float lo, float hi) {
  bf2 v = { (__bf16)lo, (__bf16)hi };         // -> v_cvt_pk_bf16_f32
  return __builtin_bit_cast(unsigned int, v);
}
__device__ __forceinline__ bf8 ldsb8(const unsigned short* p) {
  u32x4 u = *(const u32x4*)p;
  return __builtin_bit_cast(bf8, u);
}
__device__ __forceinline__ s16x4 as_bf4(u32x2 u) { return __builtin_bit_cast(s16x4, u); }
__device__ __forceinline__ f32x4 mfma16(bf8 a, bf8 b, f32x4 c) {
  return __builtin_amdgcn_mfma_f32_16x16x32_bf16(a, b, c, 0, 0, 0);
}
__device__ __forceinline__ f32x4 mfma16k(s16x4 a, s16x4 b, f32x4 c) {
  return __builtin_amdgcn_mfma_f32_16x16x16bf16_1k(a, b, c, 0, 0, 0);
}
__device__ __forceinline__ bf8 load_w8(const float* p) {   // 8 consecutive f32 -> bf8
  float4 a = ((const float4*)p)[0];
  float4 b = ((const float4*)p)[1];
  u32x4 u = { pk(a.x, a.y), pk(a.z, a.w), pk(b.x, b.y), pk(b.z, b.w) };
  return __builtin_bit_cast(bf8, u);
}
// triangular row index: i s.t. base(i) <= s < base(i+1), base(i)=i*(39-i)/2
__device__ __forceinline__ int tri_row(int s) {
  int i = (int)floorf((39.0f - sqrtf(1521.0f - 8.0f * (float)s)) * 0.5f);
  if (s < i * (39 - i) / 2) --i;
  else if (s >= (i + 1) * (38 - i) / 2) ++i;
  return i;
}

#define FOR12(M)  M(0) M(1) M(2) M(3) M(4) M(5) M(6) M(7) M(8) M(9) M(10) M(11)

__global__ void __launch_bounds__(512)
__attribute__((amdgpu_waves_per_eu(4, 4)))
tri_attn_kernel(const float* __restrict__ x, const float* __restrict__ pos,
                const float* __restrict__ w_in, const float* __restrict__ b_in,
                const float* __restrict__ w_out, const float* __restrict__ b_out,
                const float* __restrict__ ln_g, const float* __restrict__ ln_b,
                float* __restrict__ out)
{
  extern __shared__ char lds[];
  unsigned short* XT = (unsigned short*)(lds + OFF_XT);   // [190][72] x+pos; later Z
  unsigned short* OB = (unsigned short*)(lds + OFF_O);    // [190][72] Q, then O in-place
  unsigned short* VT = (unsigned short*)(lds + OFF_VT);   // [65][196] V^T + ones row

  const int tid  = threadIdx.x;
  const int lane = tid & 63;
  const int wv   = tid >> 6;      // wave = head
  const int q15  = lane & 15;
  const int g    = lane >> 4;
  const int b    = blockIdx.x;
  // (1/sqrt(8)) * log2(e): softmax via exp2, normalization cancels the base swap
  const float qscale = 0.5100694858979282f;

  // ---------------- P0: gather x + pos_emb -> XT (bf16) ----------------
  const float* xb = x + (size_t)b * (361 * 64);
  for (int idx = tid; idx < 3040; idx += 512) {            // 190 rows * 16 float4
    int s = idx >> 4, c = idx & 15;
    int i = tri_row(s);
    int j = i + s - i * (39 - i) / 2;
    float4 v = ((const float4*)(xb + (i * 19 + j) * 64))[c];
    float4 p = ((const float4*)(pos + s * 64))[c];
    u32x2 wd = { pk(v.x + p.x, v.y + p.y), pk(v.z + p.z, v.w + p.w) };
    *(u32x2*)(XT + s * XS + c * 4) = wd;
  }
  if (tid < 64) *(unsigned int*)(VT + tid * VS + 190) = 0u;  // zero VT keys 190,191
  if (tid < 98) ((unsigned int*)(VT + 64 * VS))[tid] = 0x3F803F80u;  // ones row
  __syncthreads();

  // ---------------- P1: projections ----------------
  const int t   = wv >> 1;       // head-pair row-tile (kdims 16t..16t+15)
  const int hh  = wv & 1;        // which half of the pair is my head
  const int nt  = wv & 3;        // Q/V/out-proj n-tile
  const int mtb = wv >> 2;       // Q/V/out-proj m-tile base (0 or 1)
  const bool keep = ((g >> 1) == hh);

  // named K fragments (persistent through P2)
  #define DECL_K(I) unsigned int k##I##a, k##I##b;
  FOR12(DECL_K)

  // Q = X . W_q^T (normal orientation; C: col=qdim, row=query) -> OB[query][qdim]
  {
    bf8 wq0 = load_w8(w_in + (nt * 16 + q15) * 64 + g * 8);
    bf8 wq1 = load_w8(w_in + (nt * 16 + q15) * 64 + 32 + g * 8);
    float bq = b_in[nt * 16 + q15];
    #pragma unroll
    for (int m6 = 0; m6 < 6; ++m6) {
      int mt = mtb + 2 * m6;
      f32x4 acc = {bq, bq, bq, bq};
      acc = mfma16(ldsb8(XT + (mt * 16 + q15) * XS + g * 8), wq0, acc);
      acc = mfma16(ldsb8(XT + (mt * 16 + q15) * XS + 32 + g * 8), wq1, acc);
      #pragma unroll
      for (int r = 0; r < 4; ++r) {
        int row = mt * 16 + g * 4 + r;
        if (row < 190) OB[row * OS + nt * 16 + q15] = f2b(acc[r] * qscale);
      }
    }
  }

  // K^T = W_k . X^T (C: col=key, row=kdim of the head PAIR). Kept in registers.
  {
    bf8 wk0 = load_w8(w_in + (64 + t * 16 + q15) * 64 + g * 8);
    bf8 wk1 = load_w8(w_in + (64 + t * 16 + q15) * 64 + 32 + g * 8);
    float bk0 = b_in[64 + t * 16 + g * 4 + 0], bk1 = b_in[64 + t * 16 + g * 4 + 1];
    float bk2 = b_in[64 + t * 16 + g * 4 + 2], bk3 = b_in[64 + t * 16 + g * 4 + 3];
    #define KPROJ(I) { \
      f32x4 acc = {0.f, 0.f, 0.f, 0.f}; \
      acc = mfma16(wk0, ldsb8(XT + ((I) * 16 + q15) * XS + g * 8), acc); \
      acc = mfma16(wk1, ldsb8(XT + ((I) * 16 + q15) * XS + 32 + g * 8), acc); \
      k##I##a = pk(acc[0] + bk0, acc[1] + bk1); \
      k##I##b = pk(acc[2] + bk2, acc[3] + bk3); }
    FOR12(KPROJ)
  }

  // V = X . W_v^T (C: col=vdim, row=key) -> VT[dim][key]
  {
    bf8 wv0 = load_w8(w_in + (128 + nt * 16 + q15) * 64 + g * 8);
    bf8 wv1 = load_w8(w_in + (128 + nt * 16 + q15) * 64 + 32 + g * 8);
    float bv = b_in[128 + nt * 16 + q15];
    #pragma unroll
    for (int m6 = 0; m6 < 6; ++m6) {
      int mt = mtb + 2 * m6;
      f32x4 acc = {bv, bv, bv, bv};
      acc = mfma16(ldsb8(XT + (mt * 16 + q15) * XS + g * 8), wv0, acc);
      acc = mfma16(ldsb8(XT + (mt * 16 + q15) * XS + 32 + g * 8), wv1, acc);
      unsigned int w0 = pk(acc[0], acc[1]), w1 = pk(acc[2], acc[3]);
      unsigned short* dst = VT + (nt * 16 + q15) * VS + mt * 16 + g * 4;
      if (mt == 11 && g == 3) {            // keys 188,189 only (190,191 stay 0)
        *(unsigned int*)dst = w0;
      } else {
        u32x2 wd = {w0, w1};
        *(u32x2*)dst = wd;
      }
    }
  }
  __syncthreads();

  // ---------------- P2: attention (K,V in regs; Q from LDS; O in-place) -------
  // Race-free in-place Q->O: wave h writes O only to cols h*8..h*8+7; the only
  // other wave reading those cols (its pair partner) masks them to zero (keep).
  // Softmax denom: A rows 8-15 read the VT ones row -> C rows >=8 = sum_k P = S.
  // All MFMAs here are 16x16x16 (K=16 = exactly our fragments; no padding).
  const int h = wv;
  const bool mk3 = (g == 3);
  const unsigned short* Vrow = VT + ((q15 < 8) ? (h * 8 + q15) : 64) * VS;

  // V fragments hoisted to named regs (chunk-invariant; incl. ones-row lanes)
  #define DECL_V(I) unsigned int v##I##x, v##I##y;
  FOR12(DECL_V)
  #define VLOAD(I) { \
    u32x2 t_ = *(const u32x2*)(Vrow + (I) * 16 + g * 4); \
    v##I##x = t_.x; v##I##y = t_.y; }
  FOR12(VLOAD)

  #define ATT_K(KT, OA) { \
    u32x2 ka = {k##KT##a, k##KT##b}; \
    f32x4 sc = mfma16k(as_bf4(ka), qb4, f32x4{0.f, 0.f, 0.f, 0.f}); \
    float p0 = __builtin_amdgcn_exp2f(sc[0]); \
    float p1 = __builtin_amdgcn_exp2f(sc[1]); \
    float p2 = __builtin_amdgcn_exp2f(sc[2]); \
    float p3 = __builtin_amdgcn_exp2f(sc[3]); \
    if ((KT) == 11) { p2 = mk3 ? 0.f : p2; p3 = mk3 ? 0.f : p3; } \
    u32x2 pb = {pk(p0, p1), pk(p2, p3)}; \
    u32x2 vv = {v##KT##x, v##KT##y}; \
    OA = mfma16k(as_bf4(vv), as_bf4(pb), OA); }

  #define ATT_MC(MC) { \
    u32x2 uq = *(const u32x2*)(OB + ((MC) * 16 + q15) * OS + t * 16 + g * 4); \
    u32x2 qb = {keep ? uq.x : 0u, keep ? uq.y : 0u}; \
    s16x4 qb4 = as_bf4(qb); \
    f32x4 o0 = {0.f, 0.f, 0.f, 0.f}, o1 = {0.f, 0.f, 0.f, 0.f}; \
    ATT_K(0, o0)  ATT_K(1, o1)  ATT_K(2, o0)  ATT_K(3, o1) \
    ATT_K(4, o0)  ATT_K(5, o1)  ATT_K(6, o0)  ATT_K(7, o1) \
    ATT_K(8, o0)  ATT_K(9, o1)  ATT_K(10, o0) ATT_K(11, o1) \
    f32x4 o = o0 + o1; \
    float Sv = __shfl(o[0], 32 + q15);        /* C row 8 = S, lanes 32..47 */ \
    float inv = __builtin_amdgcn_rcpf(Sv); \
    int qa = (MC) * 16 + q15; \
    if (g < 2 && qa < 190) { \
      u32x2 wd = { pk(o[0] * inv, o[1] * inv), pk(o[2] * inv, o[3] * inv) }; \
      *(u32x2*)(OB + qa * OS + h * 8 + g * 4) = wd; } }

  FOR12(ATT_MC)
  __syncthreads();

  // ---------------- P3: out-proj + residual (Z in-place into XT) ----------------
  {
    bf8 wo0 = load_w8(w_out + (nt * 16 + q15) * 64 + g * 8);
    bf8 wo1 = load_w8(w_out + (nt * 16 + q15) * 64 + 32 + g * 8);
    float bo = b_out[nt * 16 + q15];
    #pragma unroll
    for (int m6 = 0; m6 < 6; ++m6) {
      int mt = mtb + 2 * m6;
      f32x4 acc = {bo, bo, bo, bo};
      acc = mfma16(ldsb8(OB + (mt * 16 + q15) * OS + g * 8), wo0, acc);
      acc = mfma16(ldsb8(OB + (mt * 16 + q15) * OS + 32 + g * 8), wo1, acc);
      #pragma unroll
      for (int r = 0; r < 4; ++r) {
        int row = mt * 16 + g * 4 + r;
        if (row < 190) {
          int col = nt * 16 + q15;
          float z = acc[r] + b2f(XT[row * XS + col]);
          XT[row * XS + col] = f2b(z);
        }
      }
    }
  }
  __syncthreads();

  // ---------------- P4a: LN statistics via MFMA (B = ones) ----------------
  // D[m][n] = sum_k A[m,k] * 1 -- slot->k bijection cancels with B=ones.
  // Waves 0-5: tiles wv and wv+6. A: lane q15 = row, slots = dims c*16+g*4..+3.
  // C (m89, round-12-proven): row = g*4+r, col = q15 -> lanes q15==0 write stats.
  float* MU = (float*)(lds + OFF_VT);          // reuse dead VT region: [190][2] {mu, rs}
  if (wv < 6) {
    const s16x4 ones4 = { (short)0x3F80, (short)0x3F80, (short)0x3F80, (short)0x3F80 };
    #pragma unroll
    for (int half = 0; half < 2; ++half) {
      int s0 = (wv + half * 6) * 16;
      f32x4 cs = {0.f, 0.f, 0.f, 0.f};
      f32x4 cq = {0.f, 0.f, 0.f, 0.f};
      #pragma unroll
      for (int c = 0; c < 4; ++c) {
        u32x2 zz = *(const u32x2*)(XT + (s0 + q15) * XS + c * 16 + g * 4);
        cs = mfma16k(as_bf4(zz), ones4, cs);
        float f0 = b2f_lo(zz.x), f1 = b2f_hi(zz.x);
        float f2 = b2f_lo(zz.y), f3 = b2f_hi(zz.y);
        u32x2 qq = { pk(f0 * f0, f1 * f1), pk(f2 * f2, f3 * f3) };
        cq = mfma16k(as_bf4(qq), ones4, cq);
      }
      if (q15 == 0) {
        #pragma unroll
        for (int r = 0; r < 4; ++r) {
          int row = s0 + g * 4 + r;
          if (row < 190) {
            float mu = cs[r] * 0.015625f;
            float var = cq[r] * 0.015625f - mu * mu;
            float2 mr = { mu, rsqrtf(var + 1e-5f) };
            *(float2*)(MU + row * 2) = mr;
          }
        }
      }
    }
  }
  __syncthreads();

  // ---------------- P4b: normalize + symmetric scatter (shuffle-free) ---------
  {
    float gg = ln_g[lane];
    float bb = ln_b[lane];
    float* outb = out + (size_t)b * (361 * 64);
    for (int s = wv; s < 190; s += 8) {
      float2 mr = *(const float2*)(MU + s * 2);     // broadcast read (same addr)
      float zv = b2f(XT[s * XS + lane]);
      float y = (zv - mr.x) * mr.y * gg + bb;
      int i = tri_row(s);
      int j = i + s - i * (39 - i) / 2;
      outb[(i * 19 + j) * 64 + lane] = y;
      outb[(j * 19 + i) * 64 + lane] = y;           // mirror (diagonal: same value)
    }
  }
}

extern "C" void kernel_launch(void* const* d_in, const int* in_sizes, int n_in,
                              void* d_out, int out_size, void* d_ws, size_t ws_size,
                              hipStream_t stream) {
  const float* x     = (const float*)d_in[0];
  const float* pos   = (const float*)d_in[1];
  const float* w_in  = (const float*)d_in[2];
  const float* b_in  = (const float*)d_in[3];
  const float* w_out = (const float*)d_in[4];
  const float* b_out = (const float*)d_in[5];
  const float* ln_g  = (const float*)d_in[6];
  const float* ln_b  = (const float*)d_in[7];
  float* out = (float*)d_out;
  (void)in_sizes; (void)n_in; (void)out_size; (void)d_ws; (void)ws_size;
  hipFuncSetAttribute((const void*)tri_attn_kernel,
                      hipFuncAttributeMaxDynamicSharedMemorySize, LDS_BYTES);
  tri_attn_kernel<<<4096, 512, LDS_BYTES, stream>>>(x, pos, w_in, b_in, w_out,
                                                    b_out, ln_g, ln_b, out);
}

// Round 15
// 264.289 us; speedup vs baseline: 2.1908x; 1.1347x over previous
//
#include <hip/hip_runtime.h>
#include <hip/hip_bf16.h>

// ---------------------------------------------------------------------------
// TriangularSelfAttention fused kernel (round 15 = round 14 + operand pairing).
// One block per batch (4096 blocks), 512 threads = 8 waves, LDS = 81.0 KB
// (2 blocks/CU). Round-15 changes vs round 14 (passing, 300 us):
//  (1) K/V fragments stored as u32x2 vector types (even-aligned VGPR pairs)
//      instead of scalar pairs -- removes the v_mov pair-assembly before each
//      MFMA (~900+ movs/wave; counters showed ~9.6k VALU instr/wave vs ~2.7k
//      static arithmetic -> lowering overhead dominates).
//  (2) triangular scatter indices precomputed in P0 into a 760 B LDS table
//      (TRI[s] = (i*19+j) | (j*19+i)<<16); P4b drops 24 tri_row calls/wave.
// ---------------------------------------------------------------------------

typedef __bf16 bf8 __attribute__((ext_vector_type(8)));
typedef __bf16 bf2 __attribute__((ext_vector_type(2)));
typedef short s16x4 __attribute__((ext_vector_type(4)));
typedef float f32x4 __attribute__((ext_vector_type(4)));
typedef unsigned int u32x4 __attribute__((ext_vector_type(4)));
typedef unsigned int u32x2 __attribute__((ext_vector_type(2)));

#define LDS_BYTES 80960
#define OFF_XT 0
#define OFF_O  27360
#define OFF_VT 54720
#define OFF_TRI 80200   // u32[190] packed (i*19+j) | (j*19+i)<<16
#define XS 72     // XT row stride (elements)
#define OS 72     // O/Q row stride
#define VS 196    // VT row stride (rows 0..63 = v dims, row 64 = ones)

__device__ __forceinline__ unsigned short f2b(float f) {
  __bf16 h = (__bf16)f;                       // native cvt
  return __builtin_bit_cast(unsigned short, h);
}
__device__ __forceinline__ float b2f(unsigned short u) {
  unsigned int x = (unsigned int)u << 16;
  return __builtin_bit_cast(float, x);
}
__device__ __forceinline__ float b2f_lo(unsigned int u) {
  return __builtin_bit_cast(float, u << 16);
}
__device__ __forceinline__ float b2f_hi(unsigned int u) {
  return __builtin_bit_cast(float, u & 0xFFFF0000u);
}
__device__ __forceinline__ unsigned int pk(float lo, float hi) {
  bf2 v = { (__bf16)lo, (__bf16)hi };         // -> v_cvt_pk_bf16_f32
  return __builtin_bit_cast(unsigned int, v);
}
__device__ __forceinline__ bf8 ldsb8(const unsigned short* p) {
  u32x4 u = *(const u32x4*)p;
  return __builtin_bit_cast(bf8, u);
}
__device__ __forceinline__ s16x4 as_bf4(u32x2 u) { return __builtin_bit_cast(s16x4, u); }
__device__ __forceinline__ f32x4 mfma16(bf8 a, bf8 b, f32x4 c) {
  return __builtin_amdgcn_mfma_f32_16x16x32_bf16(a, b, c, 0, 0, 0);
}
__device__ __forceinline__ f32x4 mfma16k(s16x4 a, s16x4 b, f32x4 c) {
  return __builtin_amdgcn_mfma_f32_16x16x16bf16_1k(a, b, c, 0, 0, 0);
}
__device__ __forceinline__ bf8 load_w8(const float* p) {   // 8 consecutive f32 -> bf8
  float4 a = ((const float4*)p)[0];
  float4 b = ((const float4*)p)[1];
  u32x4 u = { pk(a.x, a.y), pk(a.z, a.w), pk(b.x, b.y), pk(b.z, b.w) };
  return __builtin_bit_cast(bf8, u);
}
// triangular row index: i s.t. base(i) <= s < base(i+1), base(i)=i*(39-i)/2
__device__ __forceinline__ int tri_row(int s) {
  int i = (int)floorf((39.0f - sqrtf(1521.0f - 8.0f * (float)s)) * 0.5f);
  if (s < i * (39 - i) / 2) --i;
  else if (s >= (i + 1) * (38 - i) / 2) ++i;
  return i;
}

#define FOR12(M)  M(0) M(1) M(2) M(3) M(4) M(5) M(6) M(7) M(8) M(9) M(10) M(11)

__global__ void __launch_bounds__(512)
__attribute__((amdgpu_waves_per_eu(4, 4)))
tri_attn_kernel(const float* __restrict__ x, const float* __restrict__ pos,
                const float* __restrict__ w_in, const float* __restrict__ b_in,
                const float* __restrict__ w_out, const float* __restrict__ b_out,
                const float* __restrict__ ln_g, const float* __restrict__ ln_b,
                float* __restrict__ out)
{
  extern __shared__ char lds[];
  unsigned short* XT = (unsigned short*)(lds + OFF_XT);   // [190][72] x+pos; later Z
  unsigned short* OB = (unsigned short*)(lds + OFF_O);    // [190][72] Q, then O in-place
  unsigned short* VT = (unsigned short*)(lds + OFF_VT);   // [65][196] V^T + ones row
  unsigned int*  TRI = (unsigned int*)(lds + OFF_TRI);    // [190] scatter indices

  const int tid  = threadIdx.x;
  const int lane = tid & 63;
  const int wv   = tid >> 6;      // wave = head
  const int q15  = lane & 15;
  const int g    = lane >> 4;
  const int b    = blockIdx.x;
  // (1/sqrt(8)) * log2(e): softmax via exp2, normalization cancels the base swap
  const float qscale = 0.5100694858979282f;

  // ---------------- P0: gather x + pos_emb -> XT (bf16) ----------------
  const float* xb = x + (size_t)b * (361 * 64);
  for (int idx = tid; idx < 3040; idx += 512) {            // 190 rows * 16 float4
    int s = idx >> 4, c = idx & 15;
    int i = tri_row(s);
    int j = i + s - i * (39 - i) / 2;
    float4 v = ((const float4*)(xb + (i * 19 + j) * 64))[c];
    float4 p = ((const float4*)(pos + s * 64))[c];
    u32x2 wd = { pk(v.x + p.x, v.y + p.y), pk(v.z + p.z, v.w + p.w) };
    *(u32x2*)(XT + s * XS + c * 4) = wd;
    if (c == 0)                                            // scatter table
      TRI[s] = (unsigned int)(i * 19 + j) | ((unsigned int)(j * 19 + i) << 16);
  }
  if (tid < 64) *(unsigned int*)(VT + tid * VS + 190) = 0u;  // zero VT keys 190,191
  if (tid < 98) ((unsigned int*)(VT + 64 * VS))[tid] = 0x3F803F80u;  // ones row
  __syncthreads();

  // ---------------- P1: projections ----------------
  const int t   = wv >> 1;       // head-pair row-tile (kdims 16t..16t+15)
  const int hh  = wv & 1;        // which half of the pair is my head
  const int nt  = wv & 3;        // Q/V/out-proj n-tile
  const int mtb = wv >> 2;       // Q/V/out-proj m-tile base (0 or 1)
  const bool keep = ((g >> 1) == hh);

  // named K fragments as u32x2 (even-aligned pairs; persistent through P2)
  #define DECL_K(I) u32x2 k##I;
  FOR12(DECL_K)

  // Q = X . W_q^T (normal orientation; C: col=qdim, row=query) -> OB[query][qdim]
  {
    bf8 wq0 = load_w8(w_in + (nt * 16 + q15) * 64 + g * 8);
    bf8 wq1 = load_w8(w_in + (nt * 16 + q15) * 64 + 32 + g * 8);
    float bq = b_in[nt * 16 + q15];
    #pragma unroll
    for (int m6 = 0; m6 < 6; ++m6) {
      int mt = mtb + 2 * m6;
      f32x4 acc = {bq, bq, bq, bq};
      acc = mfma16(ldsb8(XT + (mt * 16 + q15) * XS + g * 8), wq0, acc);
      acc = mfma16(ldsb8(XT + (mt * 16 + q15) * XS + 32 + g * 8), wq1, acc);
      #pragma unroll
      for (int r = 0; r < 4; ++r) {
        int row = mt * 16 + g * 4 + r;
        if (row < 190) OB[row * OS + nt * 16 + q15] = f2b(acc[r] * qscale);
      }
    }
  }

  // K^T = W_k . X^T (C: col=key, row=kdim of the head PAIR). Kept in registers.
  {
    bf8 wk0 = load_w8(w_in + (64 + t * 16 + q15) * 64 + g * 8);
    bf8 wk1 = load_w8(w_in + (64 + t * 16 + q15) * 64 + 32 + g * 8);
    float bk0 = b_in[64 + t * 16 + g * 4 + 0], bk1 = b_in[64 + t * 16 + g * 4 + 1];
    float bk2 = b_in[64 + t * 16 + g * 4 + 2], bk3 = b_in[64 + t * 16 + g * 4 + 3];
    #define KPROJ(I) { \
      f32x4 acc = {0.f, 0.f, 0.f, 0.f}; \
      acc = mfma16(wk0, ldsb8(XT + ((I) * 16 + q15) * XS + g * 8), acc); \
      acc = mfma16(wk1, ldsb8(XT + ((I) * 16 + q15) * XS + 32 + g * 8), acc); \
      k##I = u32x2{ pk(acc[0] + bk0, acc[1] + bk1), pk(acc[2] + bk2, acc[3] + bk3) }; }
    FOR12(KPROJ)
  }

  // V = X . W_v^T (C: col=vdim, row=key) -> VT[dim][key]
  {
    bf8 wv0 = load_w8(w_in + (128 + nt * 16 + q15) * 64 + g * 8);
    bf8 wv1 = load_w8(w_in + (128 + nt * 16 + q15) * 64 + 32 + g * 8);
    float bv = b_in[128 + nt * 16 + q15];
    #pragma unroll
    for (int m6 = 0; m6 < 6; ++m6) {
      int mt = mtb + 2 * m6;
      f32x4 acc = {bv, bv, bv, bv};
      acc = mfma16(ldsb8(XT + (mt * 16 + q15) * XS + g * 8), wv0, acc);
      acc = mfma16(ldsb8(XT + (mt * 16 + q15) * XS + 32 + g * 8), wv1, acc);
      unsigned int w0 = pk(acc[0], acc[1]), w1 = pk(acc[2], acc[3]);
      unsigned short* dst = VT + (nt * 16 + q15) * VS + mt * 16 + g * 4;
      if (mt == 11 && g == 3) {            // keys 188,189 only (190,191 stay 0)
        *(unsigned int*)dst = w0;
      } else {
        u32x2 wd = {w0, w1};
        *(u32x2*)dst = wd;
      }
    }
  }
  __syncthreads();

  // ---------------- P2: attention (K,V in regs; Q from LDS; O in-place) -------
  // Race-free in-place Q->O: wave h writes O only to cols h*8..h*8+7; the only
  // other wave reading those cols (its pair partner) masks them to zero (keep).
  // Softmax denom: A rows 8-15 read the VT ones row -> C rows >=8 = sum_k P = S.
  // All MFMAs here are 16x16x16 (K=16 = exactly our fragments; no padding).
  const int h = wv;
  const bool mk3 = (g == 3);
  const unsigned short* Vrow = VT + ((q15 < 8) ? (h * 8 + q15) : 64) * VS;

  // V fragments hoisted to named u32x2 regs (chunk-invariant)
  #define DECL_V(I) u32x2 v##I;
  FOR12(DECL_V)
  #define VLOAD(I) v##I = *(const u32x2*)(Vrow + (I) * 16 + g * 4);
  FOR12(VLOAD)

  #define ATT_K(KT, OA) { \
    f32x4 sc = mfma16k(as_bf4(k##KT), qb4, f32x4{0.f, 0.f, 0.f, 0.f}); \
    float p0 = __builtin_amdgcn_exp2f(sc[0]); \
    float p1 = __builtin_amdgcn_exp2f(sc[1]); \
    float p2 = __builtin_amdgcn_exp2f(sc[2]); \
    float p3 = __builtin_amdgcn_exp2f(sc[3]); \
    if ((KT) == 11) { p2 = mk3 ? 0.f : p2; p3 = mk3 ? 0.f : p3; } \
    u32x2 pb = { pk(p0, p1), pk(p2, p3) }; \
    OA = mfma16k(as_bf4(v##KT), as_bf4(pb), OA); }

  #define ATT_MC(MC) { \
    u32x2 uq = *(const u32x2*)(OB + ((MC) * 16 + q15) * OS + t * 16 + g * 4); \
    u32x2 qb = { keep ? uq.x : 0u, keep ? uq.y : 0u }; \
    s16x4 qb4 = as_bf4(qb); \
    f32x4 o0 = {0.f, 0.f, 0.f, 0.f}, o1 = {0.f, 0.f, 0.f, 0.f}; \
    ATT_K(0, o0)  ATT_K(1, o1)  ATT_K(2, o0)  ATT_K(3, o1) \
    ATT_K(4, o0)  ATT_K(5, o1)  ATT_K(6, o0)  ATT_K(7, o1) \
    ATT_K(8, o0)  ATT_K(9, o1)  ATT_K(10, o0) ATT_K(11, o1) \
    f32x4 o = o0 + o1; \
    float Sv = __shfl(o[0], 32 + q15);        /* C row 8 = S, lanes 32..47 */ \
    float inv = __builtin_amdgcn_rcpf(Sv); \
    int qa = (MC) * 16 + q15; \
    if (g < 2 && qa < 190) { \
      u32x2 wd = { pk(o[0] * inv, o[1] * inv), pk(o[2] * inv, o[3] * inv) }; \
      *(u32x2*)(OB + qa * OS + h * 8 + g * 4) = wd; } }

  FOR12(ATT_MC)
  __syncthreads();

  // ---------------- P3: out-proj + residual (Z in-place into XT) ----------------
  {
    bf8 wo0 = load_w8(w_out + (nt * 16 + q15) * 64 + g * 8);
    bf8 wo1 = load_w8(w_out + (nt * 16 + q15) * 64 + 32 + g * 8);
    float bo = b_out[nt * 16 + q15];
    #pragma unroll
    for (int m6 = 0; m6 < 6; ++m6) {
      int mt = mtb + 2 * m6;
      f32x4 acc = {bo, bo, bo, bo};
      acc = mfma16(ldsb8(OB + (mt * 16 + q15) * OS + g * 8), wo0, acc);
      acc = mfma16(ldsb8(OB + (mt * 16 + q15) * OS + 32 + g * 8), wo1, acc);
      #pragma unroll
      for (int r = 0; r < 4; ++r) {
        int row = mt * 16 + g * 4 + r;
        if (row < 190) {
          int col = nt * 16 + q15;
          float z = acc[r] + b2f(XT[row * XS + col]);
          XT[row * XS + col] = f2b(z);
        }
      }
    }
  }
  __syncthreads();

  // ---------------- P4a: LN statistics via MFMA (B = ones) ----------------
  // D[m][n] = sum_k A[m,k] * 1 -- slot->k bijection cancels with B=ones.
  // Waves 0-5: tiles wv and wv+6. A: lane q15 = row, slots = dims c*16+g*4..+3.
  // C (m89, round-12-proven): row = g*4+r, col = q15 -> lanes q15==0 write stats.
  float* MU = (float*)(lds + OFF_VT);          // reuse dead VT region: [190][2] {mu, rs}
  if (wv < 6) {
    const s16x4 ones4 = { (short)0x3F80, (short)0x3F80, (short)0x3F80, (short)0x3F80 };
    #pragma unroll
    for (int half = 0; half < 2; ++half) {
      int s0 = (wv + half * 6) * 16;
      f32x4 cs = {0.f, 0.f, 0.f, 0.f};
      f32x4 cq = {0.f, 0.f, 0.f, 0.f};
      #pragma unroll
      for (int c = 0; c < 4; ++c) {
        u32x2 zz = *(const u32x2*)(XT + (s0 + q15) * XS + c * 16 + g * 4);
        cs = mfma16k(as_bf4(zz), ones4, cs);
        float f0 = b2f_lo(zz.x), f1 = b2f_hi(zz.x);
        float f2 = b2f_lo(zz.y), f3 = b2f_hi(zz.y);
        u32x2 qq = { pk(f0 * f0, f1 * f1), pk(f2 * f2, f3 * f3) };
        cq = mfma16k(as_bf4(qq), ones4, cq);
      }
      if (q15 == 0) {
        #pragma unroll
        for (int r = 0; r < 4; ++r) {
          int row = s0 + g * 4 + r;
          if (row < 190) {
            float mu = cs[r] * 0.015625f;
            float var = cq[r] * 0.015625f - mu * mu;
            float2 mr = { mu, rsqrtf(var + 1e-5f) };
            *(float2*)(MU + row * 2) = mr;
          }
        }
      }
    }
  }
  __syncthreads();

  // ---------------- P4b: normalize + symmetric scatter (shuffle-free) ---------
  {
    float gg = ln_g[lane];
    float bb = ln_b[lane];
    float* outb = out + (size_t)b * (361 * 64);
    for (int s = wv; s < 190; s += 8) {
      float2 mr = *(const float2*)(MU + s * 2);     // broadcast read (same addr)
      unsigned int ij = TRI[s];                     // broadcast read
      float zv = b2f(XT[s * XS + lane]);
      float y = (zv - mr.x) * mr.y * gg + bb;
      outb[(ij & 0xFFFFu) * 64 + lane] = y;
      outb[(ij >> 16) * 64 + lane] = y;             // mirror (diagonal: same value)
    }
  }
}

extern "C" void kernel_launch(void* const* d_in, const int* in_sizes, int n_in,
                              void* d_out, int out_size, void* d_ws, size_t ws_size,
                              hipStream_t stream) {
  const float* x     = (const float*)d_in[0];
  const float* pos   = (const float*)d_in[1];
  const float* w_in  = (const float*)d_in[2];
  const float* b_in  = (const float*)d_in[3];
  const float* w_out = (const float*)d_in[4];
  const float* b_out = (const float*)d_in[5];
  const float* ln_g  = (const float*)d_in[6];
  const float* ln_b  = (const float*)d_in[7];
  float* out = (float*)d_out;
  (void)in_sizes; (void)n_in; (void)out_size; (void)d_ws; (void)ws_size;
  hipFuncSetAttribute((const void*)tri_attn_kernel,
                      hipFuncAttributeMaxDynamicSharedMemorySize, LDS_BYTES);
  tri_attn_kernel<<<4096, 512, LDS_BYTES, stream>>>(x, pos, w_in, b_in, w_out,
                                                    b_out, ln_g, ln_b, out);
}